// Round 14
// baseline (752.301 us; speedup 1.0000x reference)
//
#include <hip/hip_runtime.h>
#include <math.h>

#define N_NODES 8000
#define N_EDGES 24000
#define NB      256
#define ATOM    133
#define BOND    14
#define HDIM    256
#define HEADS   8
#define NLAYERS 5
#define NEG     0.2f
#define LN_EPS  1e-5f
#define HH      (HEADS * HDIM)   // 2048
#define MPAD    8064             // 63*128, padded rows for GEMM
#define EA      (N_EDGES + N_NODES)   // 32000 positions (edges + self-loops)

typedef __attribute__((ext_vector_type(8))) short short8;
typedef __attribute__((ext_vector_type(4))) float floatx4;
typedef __attribute__((ext_vector_type(2))) _Float16 h2_t;
typedef unsigned short ushort_t;

// ---------------- bf16 helpers (RNE) ----------------
__device__ __forceinline__ ushort_t f2bf(float f) {
  unsigned u = __float_as_uint(f);
  unsigned r = (u + 0x7fff + ((u >> 16) & 1)) >> 16;
  return (ushort_t)r;
}
__device__ __forceinline__ float bf2f(ushort_t h) {
  return __uint_as_float(((unsigned)h) << 16);
}
__device__ __forceinline__ float4 ldbf4(const ushort_t* p) {
  ushort4 u = *(const ushort4*)p;
  return make_float4(bf2f(u.x), bf2f(u.y), bf2f(u.z), bf2f(u.w));
}

// ---------------- f16 pair helpers ----------------
__device__ __forceinline__ h2_t u2h2(unsigned u) {
  union { unsigned u; h2_t h; } c; c.u = u; return c.h;
}
__device__ __forceinline__ unsigned f2h2(float a, float b) {
  union { h2_t h; unsigned u; } c;
  c.h.x = (_Float16)a; c.h.y = (_Float16)b;
  return c.u;
}
#if defined(__has_builtin)
#if __has_builtin(__builtin_amdgcn_fdot2)
#define FDOT2(a, b, c) __builtin_amdgcn_fdot2((a), (b), (c), false)
#endif
#endif
#ifndef FDOT2
__device__ __forceinline__ float fdot2_sw(h2_t a, h2_t b, float c) {
  return c + (float)a.x * (float)b.x + (float)a.y * (float)b.y;
}
#define FDOT2 fdot2_sw
#endif

// ---------------- DPP full-wave sum -> uniform scalar ----------------
template <int CTRL, int RMASK>
__device__ __forceinline__ float dpp_add(float x) {
  return x + __int_as_float(__builtin_amdgcn_update_dpp(
      0, __float_as_int(x), CTRL, RMASK, 0xF, true));
}
__device__ __forceinline__ float wave_sum_u(float x) {
  x = dpp_add<0xB1, 0xF>(x);    // quad_perm [1,0,3,2]  (xor 1)
  x = dpp_add<0x4E, 0xF>(x);    // quad_perm [2,3,0,1]  (xor 2)
  x = dpp_add<0x141, 0xF>(x);   // row_half_mirror      (xor 4)
  x = dpp_add<0x140, 0xF>(x);   // row_mirror           (xor 8)
  x = dpp_add<0x142, 0xA>(x);   // row_bcast15 -> rows 1,3
  x = dpp_add<0x143, 0xC>(x);   // row_bcast31 -> rows 2,3 (lane63 = total)
  return __int_as_float(__builtin_amdgcn_readlane(__float_as_int(x), 63));
}

// ---------------- async global->LDS 16B ----------------
__device__ __forceinline__ void load_lds16(const void* g, void* l) {
  __builtin_amdgcn_global_load_lds((const __attribute__((address_space(1))) unsigned int*)g,
                                   (__attribute__((address_space(3))) unsigned int*)l,
                                   16, 0, 0);
}

// ---------------- block reductions ----------------
__device__ __forceinline__ float block_reduce_sum(float v, float* red) {
  int t = threadIdx.x;
  red[t] = v; __syncthreads();
  for (int s = blockDim.x >> 1; s > 0; s >>= 1) {
    if (t < s) red[t] += red[t + s];
    __syncthreads();
  }
  float r = red[0]; __syncthreads();
  return r;
}
__device__ __forceinline__ float block_reduce_max(float v, float* red) {
  int t = threadIdx.x;
  red[t] = v; __syncthreads();
  for (int s = blockDim.x >> 1; s > 0; s >>= 1) {
    if (t < s) red[t] = fmaxf(red[t], red[t + s]);
    __syncthreads();
  }
  float r = red[0]; __syncthreads();
  return r;
}

// ---------------- CSR setup ----------------
__global__ void k_deg(const int* __restrict__ dst, int* __restrict__ deg) {
  int e = blockIdx.x * blockDim.x + threadIdx.x;
  if (e < N_EDGES) atomicAdd(&deg[dst[e]], 1);
}

// single-block exclusive scan, shfl wave-scan version
__global__ void k_scan(const int* __restrict__ cnt, int* __restrict__ offs, int n) {
  __shared__ int wsum[8];
  __shared__ int carry_s;
  int t = threadIdx.x, w = t >> 6, lane = t & 63;
  if (t == 0) carry_s = 0;
  __syncthreads();
  for (int base = 0; base < n; base += 256) {
    int i = base + t;
    int v = (i < n) ? cnt[i] : 0;
    int x = v;
#pragma unroll
    for (int off = 1; off < 64; off <<= 1) {
      int u = __shfl_up(x, off);
      if (lane >= off) x += u;
    }
    if (lane == 63) wsum[w] = x;
    __syncthreads();
    int wpre = 0;
    for (int q = 0; q < w; q++) wpre += wsum[q];
    int carry = carry_s;
    if (i < n) offs[i] = carry + wpre + x - v;
    __syncthreads();
    if (t == 255) carry_s = carry + wpre + x;
    __syncthreads();
  }
  if (t == 0) offs[n] = carry_s;
}

// fill CSR (edges scattered, self-loop tail direct)
__global__ void k_fill(const int* __restrict__ src, const int* __restrict__ dst,
                       const int* __restrict__ row_start, int* __restrict__ cursor,
                       int* __restrict__ csr_eid, int* __restrict__ csr_src) {
  int e = blockIdx.x * blockDim.x + threadIdx.x;
  if (e < N_EDGES) {
    int d = dst[e];
    int pos = atomicAdd(&cursor[d], 1);
    int q = row_start[d] + pos;
    csr_eid[q] = e;
    csr_src[q] = src[e];
  } else if (e < EA) {
    csr_src[e] = e - N_EDGES;
  }
}

__global__ void k_loop_attr(const float* __restrict__ edge_attr, const int* __restrict__ row_start,
                            const int* __restrict__ csr_eid, float* __restrict__ loop_attr) {
  int t = blockIdx.x * blockDim.x + threadIdx.x;
  if (t >= N_NODES * BOND) return;
  int i = t / BOND, k = t % BOND;
  int beg = row_start[i], end = row_start[i + 1];
  float s = 0.f;
  for (int p = beg; p < end; p++) s += edge_attr[(size_t)csr_eid[p] * BOND + k];
  int degv = end - beg;
  loop_attr[(size_t)i * BOND + k] = s / fmaxf((float)degv, 1.f);
}

// CSR-ordered f16 feature table: feat16[p][k2] = (f16 pair), 8 uints (32B) per position
__global__ void k_feat(const float* __restrict__ edge_attr, const float* __restrict__ loop_attr,
                       const int* __restrict__ csr_eid, unsigned* __restrict__ feat16) {
  int t = blockIdx.x * blockDim.x + threadIdx.x;
  if (t >= EA * 8) return;
  int p = t >> 3, k2 = t & 7;
  unsigned v = 0;
  if (k2 < 7) {
    const float* sp = (p < N_EDGES) ? (edge_attr + (size_t)csr_eid[p] * BOND)
                                    : (loop_attr + (size_t)(p - N_EDGES) * BOND);
    v = f2h2(sp[2 * k2], sp[2 * k2 + 1]);
  }
  feat16[(size_t)p * 8 + k2] = v;
}

// ---------------- build Bt: [L][4096][256] bf16 of [Wl|Wr]^T (coalesced) ----------------
__global__ __launch_bounds__(256) void k_build_bt(const float* __restrict__ Wl,
                                                  const float* __restrict__ Wr,
                                                  ushort_t* __restrict__ Bt) {
  __shared__ ushort_t s[64 * 40];
  int l = blockIdx.x >> 6;
  int n0 = (blockIdx.x & 63) * 64;
  int t = threadIdx.x;
  int nl = t & 63;
  int kr = t >> 6;
  int n = n0 + nl;
  const float* Wsrc = (n < HH) ? Wl : Wr;
  int nn = (n < HH) ? n : n - HH;
  const float* base = Wsrc + (size_t)l * HDIM * HH + nn;
  for (int kb = 0; kb < 256; kb += 32) {
#pragma unroll
    for (int q = 0; q < 8; q++) {
      int k = kb + q * 4 + kr;
      s[nl * 40 + q * 4 + kr] = f2bf(base[(size_t)k * HH]);
    }
    __syncthreads();
    {
      int n2 = t >> 2, c = t & 3;
      short8 v = *(const short8*)&s[n2 * 40 + c * 8];
      *(short8*)&Bt[((size_t)l * 4096 + n0 + n2) * 256 + kb + c * 8] = v;
    }
    __syncthreads();
  }
}

// ---------------- embedding: Linear -> LN -> ReLU, writes h + Abuf ----------------
__global__ __launch_bounds__(256) void k_embed(const float* __restrict__ x, const float* __restrict__ W,
                                               const float* __restrict__ b, const float* __restrict__ g,
                                               const float* __restrict__ beta, float* __restrict__ h,
                                               ushort_t* __restrict__ Abuf) {
  __shared__ float xs[ATOM];
  __shared__ float red[256];
  int i = blockIdx.x, j = threadIdx.x;
  if (j < ATOM) xs[j] = x[(size_t)i * ATOM + j];
  __syncthreads();
  float acc = b[j];
  for (int k = 0; k < ATOM; k++) acc += xs[k] * W[(size_t)k * HDIM + j];
  float mean = block_reduce_sum(acc, red) * (1.f / HDIM);
  float diff = acc - mean;
  float var = block_reduce_sum(diff * diff, red) * (1.f / HDIM);
  float vn = diff * rsqrtf(var + LN_EPS) * g[j] + beta[j];
  float r = fmaxf(vn, 0.f);
  h[(size_t)i * HDIM + j] = r;
  Abuf[(size_t)i * 256 + j] = f2bf(r);
}

// ---------------- MFMA GEMM: C[8064x4096] = A[Mx256] @ B[256x4096], bf16 in/out ----------------
// BK=32 double-buffer: 2 x 16KB stages (As 8KB + Bs 8KB) -> LDS block 34.8KB
// (Cs epilogue overlay dominates) -> 4 blocks/CU, 16 waves/CU.
// Stage layout: 128 rows x 32 ushorts (64B = 4 x 16B chunks per row).
__global__ __launch_bounds__(256) void k_gemm_mfma(const ushort_t* __restrict__ A,
                                                   const ushort_t* __restrict__ Bt,
                                                   ushort_t* __restrict__ C) {
  __shared__ char smem[34816];
  ushort_t* Cs = (ushort_t*)smem;                   // [128][136] epilogue overlay
  const int tid = threadIdx.x;
  const int wave = tid >> 6, lane = tid & 63;
  const int bm = blockIdx.y * 128, bn = blockIdx.x * 128;
  const int wm = (wave >> 1) * 64, wn = (wave & 1) * 64;

  const ushort_t* agA[2];
  const ushort_t* agB[2];
  int lofs[2];
#pragma unroll
  for (int j = 0; j < 2; j++) {
    int c = j * 256 + tid;             // 512 chunks of 16B per 8KB matrix stage
    int row = c >> 2, col = (c & 3) * 8;   // 4 chunks per 32-ushort row
    agA[j] = A  + (size_t)(bm + row) * 256 + col;
    agB[j] = Bt + (size_t)(bn + row) * 256 + col;
    lofs[j] = c * 8;                   // ushort offset within an 8KB half-stage
  }

  // prologue: stage 0 -> buffer 0
#pragma unroll
  for (int j = 0; j < 2; j++) load_lds16(agA[j], (ushort_t*)smem + lofs[j]);
#pragma unroll
  for (int j = 0; j < 2; j++) load_lds16(agB[j], (ushort_t*)(smem + 8192) + lofs[j]);

  floatx4 acc[4][4] = {};
  const int mrow = lane & 15;
  const int kq = (lane >> 4) * 8;

  for (int s = 0; s < 8; s++) {
    __syncthreads();
    if (s < 7) {
      char* nb = smem + ((s + 1) & 1) * 16384;
      const int k0 = (s + 1) * 32;
#pragma unroll
      for (int j = 0; j < 2; j++) load_lds16(agA[j] + k0, (ushort_t*)nb + lofs[j]);
#pragma unroll
      for (int j = 0; j < 2; j++) load_lds16(agB[j] + k0, (ushort_t*)(nb + 8192) + lofs[j]);
    }
    const ushort_t* As = (const ushort_t*)(smem + (s & 1) * 16384);
    const ushort_t* Bs = As + 4096;
    short8 af[4], bfr[4];
#pragma unroll
    for (int mi = 0; mi < 4; mi++)
      af[mi] = *(const short8*)&As[(wm + mi * 16 + mrow) * 32 + kq];
#pragma unroll
    for (int ni = 0; ni < 4; ni++)
      bfr[ni] = *(const short8*)&Bs[(wn + ni * 16 + mrow) * 32 + kq];
#pragma unroll
    for (int mi = 0; mi < 4; mi++)
#pragma unroll
      for (int ni = 0; ni < 4; ni++)
        acc[mi][ni] = __builtin_amdgcn_mfma_f32_16x16x32_bf16(af[mi], bfr[ni], acc[mi][ni], 0, 0, 0);
  }
  __syncthreads();
  const int lr = (lane >> 4) * 4, lc = lane & 15;
#pragma unroll
  for (int mi = 0; mi < 4; mi++)
#pragma unroll
    for (int ni = 0; ni < 4; ni++)
#pragma unroll
      for (int r = 0; r < 4; r++)
        Cs[(wm + mi * 16 + lr + r) * 136 + wn + ni * 16 + lc] = f2bf(acc[mi][ni][r]);
  __syncthreads();
#pragma unroll
  for (int it = 0; it < 8; it++) {
    int idx = it * 256 + tid;
    int row = idx >> 4, chunk = idx & 15;
    int grow = bm + row;
    if (grow < N_NODES) {
      short8 v = *(const short8*)&Cs[row * 136 + chunk * 8];
      *(short8*)&C[(size_t)grow * 4096 + bn + chunk * 8] = v;
    }
  }
}

// ---------------- fused attention + head-mean + bias + residual + LN ----------------
// Score returns a wave-uniform scalar (DPP reduce + readlane).
__device__ __forceinline__ float score_f16(const float4& xl, const float4& xr,
                                           const uint4& cfa, const uint4& cfb,
                                           const unsigned w2[7][4], const float4& at4) {
  float e0 = 0.f, e1 = 0.f, e2 = 0.f, e3 = 0.f;
  unsigned cf[7] = {cfa.x, cfa.y, cfa.z, cfa.w, cfb.x, cfb.y, cfb.z};
#pragma unroll
  for (int k2 = 0; k2 < 7; k2++) {
    h2_t f = u2h2(cf[k2]);
    e0 = FDOT2(f, u2h2(w2[k2][0]), e0);
    e1 = FDOT2(f, u2h2(w2[k2][1]), e1);
    e2 = FDOT2(f, u2h2(w2[k2][2]), e2);
    e3 = FDOT2(f, u2h2(w2[k2][3]), e3);
  }
  float f0 = xl.x + xr.x + e0; f0 = f0 > 0.f ? f0 : NEG * f0;
  float f1 = xl.y + xr.y + e1; f1 = f1 > 0.f ? f1 : NEG * f1;
  float f2 = xl.z + xr.z + e2; f2 = f2 > 0.f ? f2 : NEG * f2;
  float f3 = xl.w + xr.w + e3; f3 = f3 > 0.f ? f3 : NEG * f3;
  float sp = f0 * at4.x + f1 * at4.y + f2 * at4.z + f3 * at4.w;
  return wave_sum_u(sp);
}

// block = 512 threads = 8 waves (one per head); 2 nodes per block; grid = 4000.
// Dual-node interleaved chains: both nodes processed simultaneously in each wave
// (two independent score/softmax chains -> 2x ILP through the latency-bound
// reduce/exp tail). All branches wave-uniform; scores computed unconditionally
// on stale-but-safe regs when one edge list is exhausted, state updates guarded.
__global__ __launch_bounds__(512) void k_attn(const ushort_t* __restrict__ xlr,
    const unsigned* __restrict__ feat16,
    const float* __restrict__ We, const float* __restrict__ att,
    const int* __restrict__ row_start, const int* __restrict__ csr_src,
    const float* __restrict__ bias, const float* __restrict__ lng,
    const float* __restrict__ lnb,
    float* __restrict__ h, ushort_t* __restrict__ Abuf) {
  __shared__ ushort_t sacc[2][HEADS][264];
  const int tid = threadIdx.x, hh = tid >> 6, lane = tid & 63;
  unsigned w2[7][4];
#pragma unroll
  for (int k2 = 0; k2 < 7; k2++) {
    float4 a = *(const float4*)&We[(size_t)(2 * k2) * HH + hh * HDIM + lane * 4];
    float4 b = *(const float4*)&We[(size_t)(2 * k2 + 1) * HH + hh * HDIM + lane * 4];
    w2[k2][0] = f2h2(a.x, b.x); w2[k2][1] = f2h2(a.y, b.y);
    w2[k2][2] = f2h2(a.z, b.z); w2[k2][3] = f2h2(a.w, b.w);
  }
  float4 at4 = *(const float4*)&att[hh * HDIM + lane * 4];
  const int node0 = blockIdx.x * 2;
  const int iA = node0, iB = node0 + 1;
  const int begA = row_start[iA], endA = row_start[iA + 1];
  const int begB = endA, endB = row_start[iB + 1];   // CSR rows contiguous
  const int lenA = endA - begA, lenB = endB - begB;

  float4 xrA = ldbf4(&xlr[(size_t)iA * 4096 + 2048 + hh * HDIM + lane * 4]);
  float4 xrB = ldbf4(&xlr[(size_t)iB * 4096 + 2048 + hh * HDIM + lane * 4]);
  float4 xlA = ldbf4(&xlr[(size_t)iA * 4096 + hh * HDIM + lane * 4]);
  float4 xlB = ldbf4(&xlr[(size_t)iB * 4096 + hh * HDIM + lane * 4]);
  uint4 faA = *(const uint4*)&feat16[(size_t)(N_EDGES + iA) * 8];
  uint4 fbA = *(const uint4*)&feat16[(size_t)(N_EDGES + iA) * 8 + 4];
  uint4 faB = *(const uint4*)&feat16[(size_t)(N_EDGES + iB) * 8];
  uint4 fbB = *(const uint4*)&feat16[(size_t)(N_EDGES + iB) * 8 + 4];

  // depth-1 prefetch per node (init to safe values)
  float4 pxA = xlA, pxB = xlB;
  uint4 pfaA = faA, pfbA = fbA, pfaB = faB, pfbB = fbB;
  if (lenA > 0) {
    int sn = __builtin_amdgcn_readfirstlane(csr_src[begA]);
    pxA = ldbf4(&xlr[(size_t)sn * 4096 + hh * HDIM + lane * 4]);
    pfaA = *(const uint4*)&feat16[(size_t)begA * 8];
    pfbA = *(const uint4*)&feat16[(size_t)begA * 8 + 4];
  }
  if (lenB > 0) {
    int sn = __builtin_amdgcn_readfirstlane(csr_src[begB]);
    pxB = ldbf4(&xlr[(size_t)sn * 4096 + hh * HDIM + lane * 4]);
    pfaB = *(const uint4*)&feat16[(size_t)begB * 8];
    pfbB = *(const uint4*)&feat16[(size_t)begB * 8 + 4];
  }

  float mA = score_f16(xlA, xrA, faA, fbA, w2, at4);   // uniform
  float mB = score_f16(xlB, xrB, faB, fbB, w2, at4);
  float lA = 1.f, lB = 1.f;
  float oA0 = xlA.x, oA1 = xlA.y, oA2 = xlA.z, oA3 = xlA.w;
  float oB0 = xlB.x, oB1 = xlB.y, oB2 = xlB.z, oB3 = xlB.w;

  const int len = max(lenA, lenB);
  for (int t = 0; t < len; t++) {
    bool doA = t < lenA, doB = t < lenB;   // wave-uniform
    float4 xA = pxA, xB = pxB;
    uint4 cfaA = pfaA, cfbA = pfbA, cfaB = pfaB, cfbB = pfbB;
    if (t + 1 < lenA) {
      int sn = __builtin_amdgcn_readfirstlane(csr_src[begA + t + 1]);
      pxA = ldbf4(&xlr[(size_t)sn * 4096 + hh * HDIM + lane * 4]);
      pfaA = *(const uint4*)&feat16[(size_t)(begA + t + 1) * 8];
      pfbA = *(const uint4*)&feat16[(size_t)(begA + t + 1) * 8 + 4];
    }
    if (t + 1 < lenB) {
      int sn = __builtin_amdgcn_readfirstlane(csr_src[begB + t + 1]);
      pxB = ldbf4(&xlr[(size_t)sn * 4096 + hh * HDIM + lane * 4]);
      pfaB = *(const uint4*)&feat16[(size_t)(begB + t + 1) * 8];
      pfbB = *(const uint4*)&feat16[(size_t)(begB + t + 1) * 8 + 4];
    }
    // two independent chains -> interleaved by the scheduler
    float s2A = score_f16(xA, xrA, cfaA, cfbA, w2, at4);
    float s2B = score_f16(xB, xrB, cfaB, cfbB, w2, at4);
    if (doA) {
      if (s2A > mA) {
        float c = __expf(mA - s2A);
        oA0 = oA0 * c + xA.x; oA1 = oA1 * c + xA.y;
        oA2 = oA2 * c + xA.z; oA3 = oA3 * c + xA.w;
        lA = lA * c + 1.f;
        mA = s2A;
      } else {
        float wv = __expf(s2A - mA);
        oA0 += wv * xA.x; oA1 += wv * xA.y;
        oA2 += wv * xA.z; oA3 += wv * xA.w;
        lA += wv;
      }
    }
    if (doB) {
      if (s2B > mB) {
        float c = __expf(mB - s2B);
        oB0 = oB0 * c + xB.x; oB1 = oB1 * c + xB.y;
        oB2 = oB2 * c + xB.z; oB3 = oB3 * c + xB.w;
        lB = lB * c + 1.f;
        mB = s2B;
      } else {
        float wv = __expf(s2B - mB);
        oB0 += wv * xB.x; oB1 += wv * xB.y;
        oB2 += wv * xB.z; oB3 += wv * xB.w;
        lB += wv;
      }
    }
  }
  {
    float invA = 1.f / lA, invB = 1.f / lB;
    ushort4 stA, stB;
    stA.x = f2bf(oA0 * invA); stA.y = f2bf(oA1 * invA);
    stA.z = f2bf(oA2 * invA); stA.w = f2bf(oA3 * invA);
    stB.x = f2bf(oB0 * invB); stB.y = f2bf(oB1 * invB);
    stB.z = f2bf(oB2 * invB); stB.w = f2bf(oB3 * invB);
    *(ushort4*)&sacc[0][hh][lane * 4] = stA;
    *(ushort4*)&sacc[1][hh][lane * 4] = stB;
  }
  __syncthreads();
  if (hh < 2) {
    int i = node0 + hh;
    float4 hres = *(const float4*)&h[(size_t)i * HDIM + lane * 4];
    float hr[4] = {hres.x, hres.y, hres.z, hres.w};
    float v[4] = {0.f, 0.f, 0.f, 0.f};
#pragma unroll
    for (int q = 0; q < HEADS; q++) {
      ushort4 u = *(const ushort4*)&sacc[hh][q][lane * 4];
      v[0] += bf2f(u.x); v[1] += bf2f(u.y); v[2] += bf2f(u.z); v[3] += bf2f(u.w);
    }
    float4 bias4 = *(const float4*)&bias[lane * 4];
    float bi[4] = {bias4.x, bias4.y, bias4.z, bias4.w};
#pragma unroll
    for (int j = 0; j < 4; j++) v[j] = v[j] * 0.125f + bi[j] + hr[j];
    float mean = wave_sum_u(v[0] + v[1] + v[2] + v[3]) * (1.f / HDIM);
    float df[4], vr = 0.f;
#pragma unroll
    for (int j = 0; j < 4; j++) { df[j] = v[j] - mean; vr += df[j] * df[j]; }
    float rstd = rsqrtf(wave_sum_u(vr) * (1.f / HDIM) + LN_EPS);
    float4 g4 = *(const float4*)&lng[lane * 4];
    float4 b4 = *(const float4*)&lnb[lane * 4];
    float gg[4] = {g4.x, g4.y, g4.z, g4.w};
    float bb[4] = {b4.x, b4.y, b4.z, b4.w};
    float r[4];
    ushort4 hi;
#pragma unroll
    for (int j = 0; j < 4; j++) r[j] = df[j] * rstd * gg[j] + bb[j];
    hi.x = f2bf(r[0]); hi.y = f2bf(r[1]); hi.z = f2bf(r[2]); hi.w = f2bf(r[3]);
    *(float4*)&h[(size_t)i * HDIM + lane * 4] = make_float4(r[0], r[1], r[2], r[3]);
    *(ushort4*)&Abuf[(size_t)i * 256 + lane * 4] = hi;
  }
}

// ---------------- readout: gate MLP, 4 nodes per block ----------------
__global__ __launch_bounds__(128) void k_gate(const float* __restrict__ h, const float* __restrict__ g1W,
                                              const float* __restrict__ g1b, const float* __restrict__ g2W,
                                              const float* __restrict__ g2b, float* __restrict__ gate) {
  __shared__ float hs[4][HDIM];
  __shared__ float red[4][132];
  const int j = threadIdx.x;
  const int i0 = blockIdx.x * 4;
#pragma unroll
  for (int it = 0; it < 2; it++) {
    int c = it * 128 + j;
    int node = c >> 6, off = (c & 63) * 4;
    *(float4*)&hs[node][off] = *(const float4*)&h[(size_t)(i0 + node) * HDIM + off];
  }
  __syncthreads();
  float acc[4];
  float b = g1b[j];
#pragma unroll
  for (int n = 0; n < 4; n++) acc[n] = b;
  for (int k = 0; k < HDIM; k++) {
    float w = g1W[(size_t)k * (HDIM / 2) + j];
#pragma unroll
    for (int n = 0; n < 4; n++) acc[n] += hs[n][k] * w;
  }
  float w2 = g2W[j];
#pragma unroll
  for (int n = 0; n < 4; n++) red[n][j] = fmaxf(acc[n], 0.f) * w2;
  __syncthreads();
  int n = j >> 5, l2 = j & 31;
  float s = red[n][l2] + red[n][l2 + 32] + red[n][l2 + 64] + red[n][l2 + 96];
#pragma unroll
  for (int off = 16; off > 0; off >>= 1) s += __shfl_xor(s, off, 32);
  if (l2 == 0) gate[i0 + n] = s + g2b[0];
}

__global__ void k_gcount(const int* __restrict__ batch, int* __restrict__ gcnt) {
  int i = blockIdx.x * blockDim.x + threadIdx.x;
  if (i < N_NODES) atomicAdd(&gcnt[batch[i]], 1);
}

__global__ __launch_bounds__(256) void k_readout(const float* __restrict__ h, const float* __restrict__ gate,
                                                 const int* __restrict__ goff, float* __restrict__ out) {
  __shared__ float red[256];
  int b = blockIdx.x, t = threadIdx.x;
  int beg = goff[b], end = goff[b + 1];
  if (end <= beg) { out[(size_t)b * HDIM + t] = 0.f; return; }
  float lm = -3.4e38f;
  for (int i = beg + t; i < end; i += 256) lm = fmaxf(lm, gate[i]);
  float m = block_reduce_max(lm, red);
  float ls = 0.f;
  for (int i = beg + t; i < end; i += 256) ls += __expf(gate[i] - m);
  float s = block_reduce_sum(ls, red);
  float inv = 1.f / fmaxf(s, 1e-16f);
  float acc = 0.f;
  for (int i = beg; i < end; i++) acc += __expf(gate[i] - m) * h[(size_t)i * HDIM + t];
  out[(size_t)b * HDIM + t] = acc * inv;
}

// ---------------- launch ----------------
extern "C" void kernel_launch(void* const* d_in, const int* in_sizes, int n_in,
                              void* d_out, int out_size, void* d_ws, size_t ws_size,
                              hipStream_t stream) {
  const float* x         = (const float*)d_in[0];
  const float* edge_attr = (const float*)d_in[1];
  const float* emb_W     = (const float*)d_in[2];
  const float* emb_b     = (const float*)d_in[3];
  const float* emb_g     = (const float*)d_in[4];
  const float* emb_beta  = (const float*)d_in[5];
  const float* Wl        = (const float*)d_in[6];
  const float* Wr        = (const float*)d_in[7];
  const float* We        = (const float*)d_in[8];
  const float* att       = (const float*)d_in[9];
  const float* bias      = (const float*)d_in[10];
  const float* ln_g      = (const float*)d_in[11];
  const float* ln_b      = (const float*)d_in[12];
  const float* g1W       = (const float*)d_in[13];
  const float* g1b       = (const float*)d_in[14];
  const float* g2W       = (const float*)d_in[15];
  const float* g2b       = (const float*)d_in[16];
  const int*   edge_index= (const int*)d_in[17];
  const int*   batch     = (const int*)d_in[18];
  float* out = (float*)d_out;

  const int* src = edge_index;
  const int* dst = edge_index + N_EDGES;

  char* p = (char*)d_ws;
  auto alloc = [&](size_t bytes) -> void* {
    void* r = (void*)p;
    p += (bytes + 255) & ~(size_t)255;
    return r;
  };
  int*   deg       = (int*)alloc((size_t)N_NODES * 4);
  int*   row_start = (int*)alloc((size_t)(N_NODES + 1) * 4);
  int*   cursor    = (int*)alloc((size_t)N_NODES * 4);
  int*   csr_eid   = (int*)alloc((size_t)N_EDGES * 4);
  int*   csr_src   = (int*)alloc((size_t)EA * 4);
  float* loop_attr = (float*)alloc((size_t)N_NODES * BOND * 4);
  unsigned* feat16 = (unsigned*)alloc((size_t)EA * 8 * 4);
  float* h         = (float*)alloc((size_t)N_NODES * HDIM * 4);
  ushort_t* Abuf   = (ushort_t*)alloc((size_t)MPAD * 256 * 2);
  ushort_t* Bt     = (ushort_t*)alloc((size_t)NLAYERS * 4096 * 256 * 2);
  ushort_t* xlr    = (ushort_t*)alloc((size_t)N_NODES * 4096 * 2);
  float* gate      = (float*)alloc((size_t)N_NODES * 4);
  int*   gcnt      = (int*)alloc((size_t)NB * 4);
  int*   goff      = (int*)alloc((size_t)(NB + 1) * 4);

  hipMemsetAsync(deg, 0, (size_t)N_NODES * 4, stream);
  hipMemsetAsync(cursor, 0, (size_t)N_NODES * 4, stream);
  hipMemsetAsync(gcnt, 0, (size_t)NB * 4, stream);

  k_deg<<<(N_EDGES + 255) / 256, 256, 0, stream>>>(dst, deg);
  k_scan<<<1, 256, 0, stream>>>(deg, row_start, N_NODES);
  k_fill<<<(EA + 255) / 256, 256, 0, stream>>>(src, dst, row_start, cursor,
                                               csr_eid, csr_src);
  k_loop_attr<<<(N_NODES * BOND + 255) / 256, 256, 0, stream>>>(edge_attr, row_start, csr_eid, loop_attr);
  k_feat<<<(EA * 8 + 255) / 256, 256, 0, stream>>>(edge_attr, loop_attr, csr_eid, feat16);
  k_build_bt<<<NLAYERS * 64, 256, 0, stream>>>(Wl, Wr, Bt);
  k_embed<<<N_NODES, 256, 0, stream>>>(x, emb_W, emb_b, emb_g, emb_beta, h, Abuf);

  dim3 ggrid(4096 / 128, MPAD / 128);  // (32, 63)
  for (int l = 0; l < NLAYERS; l++) {
    const ushort_t* Bt_l = Bt + (size_t)l * 4096 * 256;
    const float* We_l  = We + (size_t)l * BOND * HH;
    const float* att_l = att + (size_t)l * HEADS * HDIM;
    k_gemm_mfma<<<ggrid, 256, 0, stream>>>(Abuf, Bt_l, xlr);
    k_attn<<<N_NODES / 2, 512, 0, stream>>>(xlr, feat16, We_l, att_l,
                                            row_start, csr_src,
                                            bias + (size_t)l * HDIM, ln_g + (size_t)l * HDIM,
                                            ln_b + (size_t)l * HDIM, h, Abuf);
  }

  k_gate<<<N_NODES / 4, 128, 0, stream>>>(h, g1W, g1b, g2W, g2b, gate);
  k_gcount<<<(N_NODES + 255) / 256, 256, 0, stream>>>(batch, gcnt);
  k_scan<<<1, 256, 0, stream>>>(gcnt, goff, NB);
  k_readout<<<NB, 256, 0, stream>>>(h, gate, goff, out);
}

// Round 15
// 744.912 us; speedup vs baseline: 1.0099x; 1.0099x over previous
//
#include <hip/hip_runtime.h>
#include <math.h>

#define N_NODES 8000
#define N_EDGES 24000
#define NB      256
#define ATOM    133
#define BOND    14
#define HDIM    256
#define HEADS   8
#define NLAYERS 5
#define NEG     0.2f
#define LN_EPS  1e-5f
#define HH      (HEADS * HDIM)   // 2048
#define MPAD    8064             // 63*128, padded rows for GEMM
#define EA      (N_EDGES + N_NODES)   // 32000 positions (edges + self-loops)

typedef __attribute__((ext_vector_type(8))) short short8;
typedef __attribute__((ext_vector_type(4))) float floatx4;
typedef __attribute__((ext_vector_type(2))) _Float16 h2_t;
typedef unsigned short ushort_t;

// ---------------- bf16 helpers (RNE) ----------------
__device__ __forceinline__ ushort_t f2bf(float f) {
  unsigned u = __float_as_uint(f);
  unsigned r = (u + 0x7fff + ((u >> 16) & 1)) >> 16;
  return (ushort_t)r;
}
__device__ __forceinline__ float bf2f(ushort_t h) {
  return __uint_as_float(((unsigned)h) << 16);
}
__device__ __forceinline__ float4 ldbf4(const ushort_t* p) {
  ushort4 u = *(const ushort4*)p;
  return make_float4(bf2f(u.x), bf2f(u.y), bf2f(u.z), bf2f(u.w));
}

// ---------------- f16 pair helpers ----------------
__device__ __forceinline__ h2_t u2h2(unsigned u) {
  union { unsigned u; h2_t h; } c; c.u = u; return c.h;
}
__device__ __forceinline__ unsigned f2h2(float a, float b) {
  union { h2_t h; unsigned u; } c;
  c.h.x = (_Float16)a; c.h.y = (_Float16)b;
  return c.u;
}
#if defined(__has_builtin)
#if __has_builtin(__builtin_amdgcn_fdot2)
#define FDOT2(a, b, c) __builtin_amdgcn_fdot2((a), (b), (c), false)
#endif
#endif
#ifndef FDOT2
__device__ __forceinline__ float fdot2_sw(h2_t a, h2_t b, float c) {
  return c + (float)a.x * (float)b.x + (float)a.y * (float)b.y;
}
#define FDOT2 fdot2_sw
#endif

// ---------------- DPP full-wave sum -> uniform scalar ----------------
template <int CTRL, int RMASK>
__device__ __forceinline__ float dpp_add(float x) {
  return x + __int_as_float(__builtin_amdgcn_update_dpp(
      0, __float_as_int(x), CTRL, RMASK, 0xF, true));
}
__device__ __forceinline__ float wave_sum_u(float x) {
  x = dpp_add<0xB1, 0xF>(x);    // quad_perm [1,0,3,2]  (xor 1)
  x = dpp_add<0x4E, 0xF>(x);    // quad_perm [2,3,0,1]  (xor 2)
  x = dpp_add<0x141, 0xF>(x);   // row_half_mirror      (xor 4)
  x = dpp_add<0x140, 0xF>(x);   // row_mirror           (xor 8)
  x = dpp_add<0x142, 0xA>(x);   // row_bcast15 -> rows 1,3
  x = dpp_add<0x143, 0xC>(x);   // row_bcast31 -> rows 2,3 (lane63 = total)
  return __int_as_float(__builtin_amdgcn_readlane(__float_as_int(x), 63));
}

// ---------------- async global->LDS 16B ----------------
__device__ __forceinline__ void load_lds16(const void* g, void* l) {
  __builtin_amdgcn_global_load_lds((const __attribute__((address_space(1))) unsigned int*)g,
                                   (__attribute__((address_space(3))) unsigned int*)l,
                                   16, 0, 0);
}

// ---------------- block reductions ----------------
__device__ __forceinline__ float block_reduce_sum(float v, float* red) {
  int t = threadIdx.x;
  red[t] = v; __syncthreads();
  for (int s = blockDim.x >> 1; s > 0; s >>= 1) {
    if (t < s) red[t] += red[t + s];
    __syncthreads();
  }
  float r = red[0]; __syncthreads();
  return r;
}
__device__ __forceinline__ float block_reduce_max(float v, float* red) {
  int t = threadIdx.x;
  red[t] = v; __syncthreads();
  for (int s = blockDim.x >> 1; s > 0; s >>= 1) {
    if (t < s) red[t] = fmaxf(red[t], red[t + s]);
    __syncthreads();
  }
  float r = red[0]; __syncthreads();
  return r;
}

// ---------------- CSR setup ----------------
__global__ void k_deg(const int* __restrict__ dst, int* __restrict__ deg) {
  int e = blockIdx.x * blockDim.x + threadIdx.x;
  if (e < N_EDGES) atomicAdd(&deg[dst[e]], 1);
}

// single-block exclusive scan, shfl wave-scan version
__global__ void k_scan(const int* __restrict__ cnt, int* __restrict__ offs, int n) {
  __shared__ int wsum[8];
  __shared__ int carry_s;
  int t = threadIdx.x, w = t >> 6, lane = t & 63;
  if (t == 0) carry_s = 0;
  __syncthreads();
  for (int base = 0; base < n; base += 256) {
    int i = base + t;
    int v = (i < n) ? cnt[i] : 0;
    int x = v;
#pragma unroll
    for (int off = 1; off < 64; off <<= 1) {
      int u = __shfl_up(x, off);
      if (lane >= off) x += u;
    }
    if (lane == 63) wsum[w] = x;
    __syncthreads();
    int wpre = 0;
    for (int q = 0; q < w; q++) wpre += wsum[q];
    int carry = carry_s;
    if (i < n) offs[i] = carry + wpre + x - v;
    __syncthreads();
    if (t == 255) carry_s = carry + wpre + x;
    __syncthreads();
  }
  if (t == 0) offs[n] = carry_s;
}

// fill CSR (edges scattered, self-loop tail direct)
__global__ void k_fill(const int* __restrict__ src, const int* __restrict__ dst,
                       const int* __restrict__ row_start, int* __restrict__ cursor,
                       int* __restrict__ csr_eid, int* __restrict__ csr_src) {
  int e = blockIdx.x * blockDim.x + threadIdx.x;
  if (e < N_EDGES) {
    int d = dst[e];
    int pos = atomicAdd(&cursor[d], 1);
    int q = row_start[d] + pos;
    csr_eid[q] = e;
    csr_src[q] = src[e];
  } else if (e < EA) {
    csr_src[e] = e - N_EDGES;
  }
}

__global__ void k_loop_attr(const float* __restrict__ edge_attr, const int* __restrict__ row_start,
                            const int* __restrict__ csr_eid, float* __restrict__ loop_attr) {
  int t = blockIdx.x * blockDim.x + threadIdx.x;
  if (t >= N_NODES * BOND) return;
  int i = t / BOND, k = t % BOND;
  int beg = row_start[i], end = row_start[i + 1];
  float s = 0.f;
  for (int p = beg; p < end; p++) s += edge_attr[(size_t)csr_eid[p] * BOND + k];
  int degv = end - beg;
  loop_attr[(size_t)i * BOND + k] = s / fmaxf((float)degv, 1.f);
}

// CSR-ordered f16 feature table: feat16[p][k2] = (f16 pair), 8 uints (32B) per position
__global__ void k_feat(const float* __restrict__ edge_attr, const float* __restrict__ loop_attr,
                       const int* __restrict__ csr_eid, unsigned* __restrict__ feat16) {
  int t = blockIdx.x * blockDim.x + threadIdx.x;
  if (t >= EA * 8) return;
  int p = t >> 3, k2 = t & 7;
  unsigned v = 0;
  if (k2 < 7) {
    const float* sp = (p < N_EDGES) ? (edge_attr + (size_t)csr_eid[p] * BOND)
                                    : (loop_attr + (size_t)(p - N_EDGES) * BOND);
    v = f2h2(sp[2 * k2], sp[2 * k2 + 1]);
  }
  feat16[(size_t)p * 8 + k2] = v;
}

// ---------------- build Bt: [L][4096][256] bf16 of [Wl|Wr]^T (coalesced) ----------------
__global__ __launch_bounds__(256) void k_build_bt(const float* __restrict__ Wl,
                                                  const float* __restrict__ Wr,
                                                  ushort_t* __restrict__ Bt) {
  __shared__ ushort_t s[64 * 40];
  int l = blockIdx.x >> 6;
  int n0 = (blockIdx.x & 63) * 64;
  int t = threadIdx.x;
  int nl = t & 63;
  int kr = t >> 6;
  int n = n0 + nl;
  const float* Wsrc = (n < HH) ? Wl : Wr;
  int nn = (n < HH) ? n : n - HH;
  const float* base = Wsrc + (size_t)l * HDIM * HH + nn;
  for (int kb = 0; kb < 256; kb += 32) {
#pragma unroll
    for (int q = 0; q < 8; q++) {
      int k = kb + q * 4 + kr;
      s[nl * 40 + q * 4 + kr] = f2bf(base[(size_t)k * HH]);
    }
    __syncthreads();
    {
      int n2 = t >> 2, c = t & 3;
      short8 v = *(const short8*)&s[n2 * 40 + c * 8];
      *(short8*)&Bt[((size_t)l * 4096 + n0 + n2) * 256 + kb + c * 8] = v;
    }
    __syncthreads();
  }
}

// ---------------- embedding: Linear -> LN -> ReLU, writes h + Abuf ----------------
__global__ __launch_bounds__(256) void k_embed(const float* __restrict__ x, const float* __restrict__ W,
                                               const float* __restrict__ b, const float* __restrict__ g,
                                               const float* __restrict__ beta, float* __restrict__ h,
                                               ushort_t* __restrict__ Abuf) {
  __shared__ float xs[ATOM];
  __shared__ float red[256];
  int i = blockIdx.x, j = threadIdx.x;
  if (j < ATOM) xs[j] = x[(size_t)i * ATOM + j];
  __syncthreads();
  float acc = b[j];
  for (int k = 0; k < ATOM; k++) acc += xs[k] * W[(size_t)k * HDIM + j];
  float mean = block_reduce_sum(acc, red) * (1.f / HDIM);
  float diff = acc - mean;
  float var = block_reduce_sum(diff * diff, red) * (1.f / HDIM);
  float vn = diff * rsqrtf(var + LN_EPS) * g[j] + beta[j];
  float r = fmaxf(vn, 0.f);
  h[(size_t)i * HDIM + j] = r;
  Abuf[(size_t)i * 256 + j] = f2bf(r);
}

// ---------------- MFMA GEMM: C[8064x4096] = A[Mx256] @ B[256x4096], bf16 in/out ----------------
// BK=32 double-buffer: 2 x 16KB stages; stage = 128 rows x 32 ushorts (4 x 16B/row).
__global__ __launch_bounds__(256) void k_gemm_mfma(const ushort_t* __restrict__ A,
                                                   const ushort_t* __restrict__ Bt,
                                                   ushort_t* __restrict__ C) {
  __shared__ char smem[34816];
  ushort_t* Cs = (ushort_t*)smem;                   // [128][136] epilogue overlay
  const int tid = threadIdx.x;
  const int wave = tid >> 6, lane = tid & 63;
  const int bm = blockIdx.y * 128, bn = blockIdx.x * 128;
  const int wm = (wave >> 1) * 64, wn = (wave & 1) * 64;

  const ushort_t* agA[2];
  const ushort_t* agB[2];
  int lofs[2];
#pragma unroll
  for (int j = 0; j < 2; j++) {
    int c = j * 256 + tid;
    int row = c >> 2, col = (c & 3) * 8;
    agA[j] = A  + (size_t)(bm + row) * 256 + col;
    agB[j] = Bt + (size_t)(bn + row) * 256 + col;
    lofs[j] = c * 8;
  }

#pragma unroll
  for (int j = 0; j < 2; j++) load_lds16(agA[j], (ushort_t*)smem + lofs[j]);
#pragma unroll
  for (int j = 0; j < 2; j++) load_lds16(agB[j], (ushort_t*)(smem + 8192) + lofs[j]);

  floatx4 acc[4][4] = {};
  const int mrow = lane & 15;
  const int kq = (lane >> 4) * 8;

  for (int s = 0; s < 8; s++) {
    __syncthreads();
    if (s < 7) {
      char* nb = smem + ((s + 1) & 1) * 16384;
      const int k0 = (s + 1) * 32;
#pragma unroll
      for (int j = 0; j < 2; j++) load_lds16(agA[j] + k0, (ushort_t*)nb + lofs[j]);
#pragma unroll
      for (int j = 0; j < 2; j++) load_lds16(agB[j] + k0, (ushort_t*)(nb + 8192) + lofs[j]);
    }
    const ushort_t* As = (const ushort_t*)(smem + (s & 1) * 16384);
    const ushort_t* Bs = As + 4096;
    short8 af[4], bfr[4];
#pragma unroll
    for (int mi = 0; mi < 4; mi++)
      af[mi] = *(const short8*)&As[(wm + mi * 16 + mrow) * 32 + kq];
#pragma unroll
    for (int ni = 0; ni < 4; ni++)
      bfr[ni] = *(const short8*)&Bs[(wn + ni * 16 + mrow) * 32 + kq];
#pragma unroll
    for (int mi = 0; mi < 4; mi++)
#pragma unroll
      for (int ni = 0; ni < 4; ni++)
        acc[mi][ni] = __builtin_amdgcn_mfma_f32_16x16x32_bf16(af[mi], bfr[ni], acc[mi][ni], 0, 0, 0);
  }
  __syncthreads();
  const int lr = (lane >> 4) * 4, lc = lane & 15;
#pragma unroll
  for (int mi = 0; mi < 4; mi++)
#pragma unroll
    for (int ni = 0; ni < 4; ni++)
#pragma unroll
      for (int r = 0; r < 4; r++)
        Cs[(wm + mi * 16 + lr + r) * 136 + wn + ni * 16 + lc] = f2bf(acc[mi][ni][r]);
  __syncthreads();
#pragma unroll
  for (int it = 0; it < 8; it++) {
    int idx = it * 256 + tid;
    int row = idx >> 4, chunk = idx & 15;
    int grow = bm + row;
    if (grow < N_NODES) {
      short8 v = *(const short8*)&Cs[row * 136 + chunk * 8];
      *(short8*)&C[(size_t)grow * 4096 + bn + chunk * 8] = v;
    }
  }
}

// ---------------- fused attention + head-mean + bias + residual + LN ----------------
// Score returns a wave-uniform scalar (DPP reduce + readlane).
__device__ __forceinline__ float score_f16(const float4& xl, const float4& xr,
                                           const uint4& cfa, const uint4& cfb,
                                           const unsigned w2[7][4], const float4& at4) {
  float e0 = 0.f, e1 = 0.f, e2 = 0.f, e3 = 0.f;
  unsigned cf[7] = {cfa.x, cfa.y, cfa.z, cfa.w, cfb.x, cfb.y, cfb.z};
#pragma unroll
  for (int k2 = 0; k2 < 7; k2++) {
    h2_t f = u2h2(cf[k2]);
    e0 = FDOT2(f, u2h2(w2[k2][0]), e0);
    e1 = FDOT2(f, u2h2(w2[k2][1]), e1);
    e2 = FDOT2(f, u2h2(w2[k2][2]), e2);
    e3 = FDOT2(f, u2h2(w2[k2][3]), e3);
  }
  float f0 = xl.x + xr.x + e0; f0 = f0 > 0.f ? f0 : NEG * f0;
  float f1 = xl.y + xr.y + e1; f1 = f1 > 0.f ? f1 : NEG * f1;
  float f2 = xl.z + xr.z + e2; f2 = f2 > 0.f ? f2 : NEG * f2;
  float f3 = xl.w + xr.w + e3; f3 = f3 > 0.f ? f3 : NEG * f3;
  float sp = f0 * at4.x + f1 * at4.y + f2 * at4.z + f3 * at4.w;
  return wave_sum_u(sp);
}

// block = 512 threads = 8 waves (one per head); 2 nodes per block; grid = 4000.
// Per node: the edge list is SPLIT INTO TWO HALF-CHAINS (A = [0,half), B =
// [half,len)) with independent online-softmax state, merged exactly at the end.
// 2x ILP through the reduce/exp tail with perfect balance (<=1 wasted slot).
__global__ __launch_bounds__(512) void k_attn(const ushort_t* __restrict__ xlr,
    const unsigned* __restrict__ feat16,
    const float* __restrict__ We, const float* __restrict__ att,
    const int* __restrict__ row_start, const int* __restrict__ csr_src,
    const float* __restrict__ bias, const float* __restrict__ lng,
    const float* __restrict__ lnb,
    float* __restrict__ h, ushort_t* __restrict__ Abuf) {
  __shared__ ushort_t sacc[2][HEADS][264];
  const int tid = threadIdx.x, hh = tid >> 6, lane = tid & 63;
  unsigned w2[7][4];
#pragma unroll
  for (int k2 = 0; k2 < 7; k2++) {
    float4 a = *(const float4*)&We[(size_t)(2 * k2) * HH + hh * HDIM + lane * 4];
    float4 b = *(const float4*)&We[(size_t)(2 * k2 + 1) * HH + hh * HDIM + lane * 4];
    w2[k2][0] = f2h2(a.x, b.x); w2[k2][1] = f2h2(a.y, b.y);
    w2[k2][2] = f2h2(a.z, b.z); w2[k2][3] = f2h2(a.w, b.w);
  }
  float4 at4 = *(const float4*)&att[hh * HDIM + lane * 4];
  const int node0 = blockIdx.x * 2;

#pragma unroll
  for (int ni = 0; ni < 2; ni++) {
    int i = node0 + ni;
    int beg = row_start[i], end = row_start[i + 1];
    int len = end - beg;
    int half = (len + 1) >> 1;           // chain A: [beg, beg+half), chain B: [beg+half, end)
    int lenB = len - half;
    float4 xr4 = ldbf4(&xlr[(size_t)i * 4096 + 2048 + hh * HDIM + lane * 4]);
    float4 xl4 = ldbf4(&xlr[(size_t)i * 4096 + hh * HDIM + lane * 4]);
    int pself = N_EDGES + i;
    uint4 fsa = *(const uint4*)&feat16[(size_t)pself * 8];
    uint4 fsb = *(const uint4*)&feat16[(size_t)pself * 8 + 4];

    // depth-1 prefetch for both chains (init to safe values)
    float4 pxA = xl4, pxB = xl4;
    uint4 pfaA = fsa, pfbA = fsb, pfaB = fsa, pfbB = fsb;
    if (half > 0) {
      int sn = __builtin_amdgcn_readfirstlane(csr_src[beg]);
      pxA = ldbf4(&xlr[(size_t)sn * 4096 + hh * HDIM + lane * 4]);
      pfaA = *(const uint4*)&feat16[(size_t)beg * 8];
      pfbA = *(const uint4*)&feat16[(size_t)beg * 8 + 4];
    }
    if (lenB > 0) {
      int sn = __builtin_amdgcn_readfirstlane(csr_src[beg + half]);
      pxB = ldbf4(&xlr[(size_t)sn * 4096 + hh * HDIM + lane * 4]);
      pfaB = *(const uint4*)&feat16[(size_t)(beg + half) * 8];
      pfbB = *(const uint4*)&feat16[(size_t)(beg + half) * 8 + 4];
    }

    // chain A seeded with the self-loop; chain B empty
    float mA = score_f16(xl4, xr4, fsa, fsb, w2, at4);   // uniform
    float lA = 1.f;
    float oA0 = xl4.x, oA1 = xl4.y, oA2 = xl4.z, oA3 = xl4.w;
    float mB = -3.4e38f, lB = 0.f;
    float oB0 = 0.f, oB1 = 0.f, oB2 = 0.f, oB3 = 0.f;

    for (int t = 0; t < half; t++) {
      bool doB = t < lenB;               // wave-uniform; chain A always active
      float4 xA = pxA, xB = pxB;
      uint4 cfaA = pfaA, cfbA = pfbA, cfaB = pfaB, cfbB = pfbB;
      if (t + 1 < half) {
        int sn = __builtin_amdgcn_readfirstlane(csr_src[beg + t + 1]);
        pxA = ldbf4(&xlr[(size_t)sn * 4096 + hh * HDIM + lane * 4]);
        pfaA = *(const uint4*)&feat16[(size_t)(beg + t + 1) * 8];
        pfbA = *(const uint4*)&feat16[(size_t)(beg + t + 1) * 8 + 4];
      }
      if (t + 1 < lenB) {
        int sn = __builtin_amdgcn_readfirstlane(csr_src[beg + half + t + 1]);
        pxB = ldbf4(&xlr[(size_t)sn * 4096 + hh * HDIM + lane * 4]);
        pfaB = *(const uint4*)&feat16[(size_t)(beg + half + t + 1) * 8];
        pfbB = *(const uint4*)&feat16[(size_t)(beg + half + t + 1) * 8 + 4];
      }
      // two independent chains -> interleaved by the scheduler
      float sA = score_f16(xA, xr4, cfaA, cfbA, w2, at4);
      float sB = score_f16(xB, xr4, cfaB, cfbB, w2, at4);
      {
        if (sA > mA) {
          float c = __expf(mA - sA);
          oA0 = oA0 * c + xA.x; oA1 = oA1 * c + xA.y;
          oA2 = oA2 * c + xA.z; oA3 = oA3 * c + xA.w;
          lA = lA * c + 1.f;
          mA = sA;
        } else {
          float wv = __expf(sA - mA);
          oA0 += wv * xA.x; oA1 += wv * xA.y;
          oA2 += wv * xA.z; oA3 += wv * xA.w;
          lA += wv;
        }
      }
      if (doB) {
        if (sB > mB) {
          float c = (lB > 0.f) ? __expf(mB - sB) : 0.f;
          oB0 = oB0 * c + xB.x; oB1 = oB1 * c + xB.y;
          oB2 = oB2 * c + xB.z; oB3 = oB3 * c + xB.w;
          lB = lB * c + 1.f;
          mB = sB;
        } else {
          float wv = __expf(sB - mB);
          oB0 += wv * xB.x; oB1 += wv * xB.y;
          oB2 += wv * xB.z; oB3 += wv * xB.w;
          lB += wv;
        }
      }
    }
    // exact split-softmax merge (all scalars uniform)
    float mm = fmaxf(mA, mB);
    float cA = __expf(mA - mm);
    float cB = (lB > 0.f) ? __expf(mB - mm) : 0.f;
    float l = lA * cA + lB * cB;
    float o0 = oA0 * cA + oB0 * cB;
    float o1 = oA1 * cA + oB1 * cB;
    float o2 = oA2 * cA + oB2 * cB;
    float o3 = oA3 * cA + oB3 * cB;
    float inv = 1.f / l;
    ushort4 st;
    st.x = f2bf(o0 * inv); st.y = f2bf(o1 * inv);
    st.z = f2bf(o2 * inv); st.w = f2bf(o3 * inv);
    *(ushort4*)&sacc[ni][hh][lane * 4] = st;
  }
  __syncthreads();
  if (hh < 2) {
    int i = node0 + hh;
    float4 hres = *(const float4*)&h[(size_t)i * HDIM + lane * 4];
    float hr[4] = {hres.x, hres.y, hres.z, hres.w};
    float v[4] = {0.f, 0.f, 0.f, 0.f};
#pragma unroll
    for (int q = 0; q < HEADS; q++) {
      ushort4 u = *(const ushort4*)&sacc[hh][q][lane * 4];
      v[0] += bf2f(u.x); v[1] += bf2f(u.y); v[2] += bf2f(u.z); v[3] += bf2f(u.w);
    }
    float4 bias4 = *(const float4*)&bias[lane * 4];
    float bi[4] = {bias4.x, bias4.y, bias4.z, bias4.w};
#pragma unroll
    for (int j = 0; j < 4; j++) v[j] = v[j] * 0.125f + bi[j] + hr[j];
    float mean = wave_sum_u(v[0] + v[1] + v[2] + v[3]) * (1.f / HDIM);
    float df[4], vr = 0.f;
#pragma unroll
    for (int j = 0; j < 4; j++) { df[j] = v[j] - mean; vr += df[j] * df[j]; }
    float rstd = rsqrtf(wave_sum_u(vr) * (1.f / HDIM) + LN_EPS);
    float4 g4 = *(const float4*)&lng[lane * 4];
    float4 b4 = *(const float4*)&lnb[lane * 4];
    float gg[4] = {g4.x, g4.y, g4.z, g4.w};
    float bb[4] = {b4.x, b4.y, b4.z, b4.w};
    float r[4];
    ushort4 hi;
#pragma unroll
    for (int j = 0; j < 4; j++) r[j] = df[j] * rstd * gg[j] + bb[j];
    hi.x = f2bf(r[0]); hi.y = f2bf(r[1]); hi.z = f2bf(r[2]); hi.w = f2bf(r[3]);
    *(float4*)&h[(size_t)i * HDIM + lane * 4] = make_float4(r[0], r[1], r[2], r[3]);
    *(ushort4*)&Abuf[(size_t)i * 256 + lane * 4] = hi;
  }
}

// ---------------- readout: gate MLP, 4 nodes per block ----------------
__global__ __launch_bounds__(128) void k_gate(const float* __restrict__ h, const float* __restrict__ g1W,
                                              const float* __restrict__ g1b, const float* __restrict__ g2W,
                                              const float* __restrict__ g2b, float* __restrict__ gate) {
  __shared__ float hs[4][HDIM];
  __shared__ float red[4][132];
  const int j = threadIdx.x;
  const int i0 = blockIdx.x * 4;
#pragma unroll
  for (int it = 0; it < 2; it++) {
    int c = it * 128 + j;
    int node = c >> 6, off = (c & 63) * 4;
    *(float4*)&hs[node][off] = *(const float4*)&h[(size_t)(i0 + node) * HDIM + off];
  }
  __syncthreads();
  float acc[4];
  float b = g1b[j];
#pragma unroll
  for (int n = 0; n < 4; n++) acc[n] = b;
  for (int k = 0; k < HDIM; k++) {
    float w = g1W[(size_t)k * (HDIM / 2) + j];
#pragma unroll
    for (int n = 0; n < 4; n++) acc[n] += hs[n][k] * w;
  }
  float w2 = g2W[j];
#pragma unroll
  for (int n = 0; n < 4; n++) red[n][j] = fmaxf(acc[n], 0.f) * w2;
  __syncthreads();
  int n = j >> 5, l2 = j & 31;
  float s = red[n][l2] + red[n][l2 + 32] + red[n][l2 + 64] + red[n][l2 + 96];
#pragma unroll
  for (int off = 16; off > 0; off >>= 1) s += __shfl_xor(s, off, 32);
  if (l2 == 0) gate[i0 + n] = s + g2b[0];
}

__global__ void k_gcount(const int* __restrict__ batch, int* __restrict__ gcnt) {
  int i = blockIdx.x * blockDim.x + threadIdx.x;
  if (i < N_NODES) atomicAdd(&gcnt[batch[i]], 1);
}

__global__ __launch_bounds__(256) void k_readout(const float* __restrict__ h, const float* __restrict__ gate,
                                                 const int* __restrict__ goff, float* __restrict__ out) {
  __shared__ float red[256];
  int b = blockIdx.x, t = threadIdx.x;
  int beg = goff[b], end = goff[b + 1];
  if (end <= beg) { out[(size_t)b * HDIM + t] = 0.f; return; }
  float lm = -3.4e38f;
  for (int i = beg + t; i < end; i += 256) lm = fmaxf(lm, gate[i]);
  float m = block_reduce_max(lm, red);
  float ls = 0.f;
  for (int i = beg + t; i < end; i += 256) ls += __expf(gate[i] - m);
  float s = block_reduce_sum(ls, red);
  float inv = 1.f / fmaxf(s, 1e-16f);
  float acc = 0.f;
  for (int i = beg; i < end; i++) acc += __expf(gate[i] - m) * h[(size_t)i * HDIM + t];
  out[(size_t)b * HDIM + t] = acc * inv;
}

// ---------------- launch ----------------
extern "C" void kernel_launch(void* const* d_in, const int* in_sizes, int n_in,
                              void* d_out, int out_size, void* d_ws, size_t ws_size,
                              hipStream_t stream) {
  const float* x         = (const float*)d_in[0];
  const float* edge_attr = (const float*)d_in[1];
  const float* emb_W     = (const float*)d_in[2];
  const float* emb_b     = (const float*)d_in[3];
  const float* emb_g     = (const float*)d_in[4];
  const float* emb_beta  = (const float*)d_in[5];
  const float* Wl        = (const float*)d_in[6];
  const float* Wr        = (const float*)d_in[7];
  const float* We        = (const float*)d_in[8];
  const float* att       = (const float*)d_in[9];
  const float* bias      = (const float*)d_in[10];
  const float* ln_g      = (const float*)d_in[11];
  const float* ln_b      = (const float*)d_in[12];
  const float* g1W       = (const float*)d_in[13];
  const float* g1b       = (const float*)d_in[14];
  const float* g2W       = (const float*)d_in[15];
  const float* g2b       = (const float*)d_in[16];
  const int*   edge_index= (const int*)d_in[17];
  const int*   batch     = (const int*)d_in[18];
  float* out = (float*)d_out;

  const int* src = edge_index;
  const int* dst = edge_index + N_EDGES;

  char* p = (char*)d_ws;
  auto alloc = [&](size_t bytes) -> void* {
    void* r = (void*)p;
    p += (bytes + 255) & ~(size_t)255;
    return r;
  };
  int*   deg       = (int*)alloc((size_t)N_NODES * 4);
  int*   row_start = (int*)alloc((size_t)(N_NODES + 1) * 4);
  int*   cursor    = (int*)alloc((size_t)N_NODES * 4);
  int*   csr_eid   = (int*)alloc((size_t)N_EDGES * 4);
  int*   csr_src   = (int*)alloc((size_t)EA * 4);
  float* loop_attr = (float*)alloc((size_t)N_NODES * BOND * 4);
  unsigned* feat16 = (unsigned*)alloc((size_t)EA * 8 * 4);
  float* h         = (float*)alloc((size_t)N_NODES * HDIM * 4);
  ushort_t* Abuf   = (ushort_t*)alloc((size_t)MPAD * 256 * 2);
  ushort_t* Bt     = (ushort_t*)alloc((size_t)NLAYERS * 4096 * 256 * 2);
  ushort_t* xlr    = (ushort_t*)alloc((size_t)N_NODES * 4096 * 2);
  float* gate      = (float*)alloc((size_t)N_NODES * 4);
  int*   gcnt      = (int*)alloc((size_t)NB * 4);
  int*   goff      = (int*)alloc((size_t)(NB + 1) * 4);

  hipMemsetAsync(deg, 0, (size_t)N_NODES * 4, stream);
  hipMemsetAsync(cursor, 0, (size_t)N_NODES * 4, stream);
  hipMemsetAsync(gcnt, 0, (size_t)NB * 4, stream);

  k_deg<<<(N_EDGES + 255) / 256, 256, 0, stream>>>(dst, deg);
  k_scan<<<1, 256, 0, stream>>>(deg, row_start, N_NODES);
  k_fill<<<(EA + 255) / 256, 256, 0, stream>>>(src, dst, row_start, cursor,
                                               csr_eid, csr_src);
  k_loop_attr<<<(N_NODES * BOND + 255) / 256, 256, 0, stream>>>(edge_attr, row_start, csr_eid, loop_attr);
  k_feat<<<(EA * 8 + 255) / 256, 256, 0, stream>>>(edge_attr, loop_attr, csr_eid, feat16);
  k_build_bt<<<NLAYERS * 64, 256, 0, stream>>>(Wl, Wr, Bt);
  k_embed<<<N_NODES, 256, 0, stream>>>(x, emb_W, emb_b, emb_g, emb_beta, h, Abuf);

  dim3 ggrid(4096 / 128, MPAD / 128);  // (32, 63)
  for (int l = 0; l < NLAYERS; l++) {
    const ushort_t* Bt_l = Bt + (size_t)l * 4096 * 256;
    const float* We_l  = We + (size_t)l * BOND * HH;
    const float* att_l = att + (size_t)l * HEADS * HDIM;
    k_gemm_mfma<<<ggrid, 256, 0, stream>>>(Abuf, Bt_l, xlr);
    k_attn<<<N_NODES / 2, 512, 0, stream>>>(xlr, feat16, We_l, att_l,
                                            row_start, csr_src,
                                            bias + (size_t)l * HDIM, ln_g + (size_t)l * HDIM,
                                            ln_b + (size_t)l * HDIM, h, Abuf);
  }

  k_gate<<<N_NODES / 4, 128, 0, stream>>>(h, g1W, g1b, g2W, g2b, gate);
  k_gcount<<<(N_NODES + 255) / 256, 256, 0, stream>>>(batch, gcnt);
  k_scan<<<1, 256, 0, stream>>>(gcnt, goff, NB);
  k_readout<<<NB, 256, 0, stream>>>(h, gate, goff, out);
}

// Round 16
// 708.324 us; speedup vs baseline: 1.0621x; 1.0517x over previous
//
#include <hip/hip_runtime.h>
#include <math.h>

#define N_NODES 8000
#define N_EDGES 24000
#define NB      256
#define ATOM    133
#define BOND    14
#define HDIM    256
#define HEADS   8
#define NLAYERS 5
#define NEG     0.2f
#define LN_EPS  1e-5f
#define HH      (HEADS * HDIM)   // 2048
#define MPAD    8064             // 63*128, padded rows for GEMM
#define EA      (N_EDGES + N_NODES)   // 32000 positions (edges + self-loops)

typedef __attribute__((ext_vector_type(8))) short short8;
typedef __attribute__((ext_vector_type(4))) float floatx4;
typedef __attribute__((ext_vector_type(2))) _Float16 h2_t;
typedef unsigned short ushort_t;

// ---------------- bf16 helpers (RNE) ----------------
__device__ __forceinline__ ushort_t f2bf(float f) {
  unsigned u = __float_as_uint(f);
  unsigned r = (u + 0x7fff + ((u >> 16) & 1)) >> 16;
  return (ushort_t)r;
}
__device__ __forceinline__ float bf2f(ushort_t h) {
  return __uint_as_float(((unsigned)h) << 16);
}
__device__ __forceinline__ float4 ldbf4(const ushort_t* p) {
  ushort4 u = *(const ushort4*)p;
  return make_float4(bf2f(u.x), bf2f(u.y), bf2f(u.z), bf2f(u.w));
}

// ---------------- f16 pair helpers ----------------
__device__ __forceinline__ h2_t u2h2(unsigned u) {
  union { unsigned u; h2_t h; } c; c.u = u; return c.h;
}
__device__ __forceinline__ unsigned f2h2(float a, float b) {
  union { h2_t h; unsigned u; } c;
  c.h.x = (_Float16)a; c.h.y = (_Float16)b;
  return c.u;
}
#if defined(__has_builtin)
#if __has_builtin(__builtin_amdgcn_fdot2)
#define FDOT2(a, b, c) __builtin_amdgcn_fdot2((a), (b), (c), false)
#endif
#endif
#ifndef FDOT2
__device__ __forceinline__ float fdot2_sw(h2_t a, h2_t b, float c) {
  return c + (float)a.x * (float)b.x + (float)a.y * (float)b.y;
}
#define FDOT2 fdot2_sw
#endif

// ---------------- DPP full-wave sum -> uniform scalar ----------------
template <int CTRL, int RMASK>
__device__ __forceinline__ float dpp_add(float x) {
  return x + __int_as_float(__builtin_amdgcn_update_dpp(
      0, __float_as_int(x), CTRL, RMASK, 0xF, true));
}
__device__ __forceinline__ float wave_sum_u(float x) {
  x = dpp_add<0xB1, 0xF>(x);    // quad_perm [1,0,3,2]  (xor 1)
  x = dpp_add<0x4E, 0xF>(x);    // quad_perm [2,3,0,1]  (xor 2)
  x = dpp_add<0x141, 0xF>(x);   // row_half_mirror      (xor 4)
  x = dpp_add<0x140, 0xF>(x);   // row_mirror           (xor 8)
  x = dpp_add<0x142, 0xA>(x);   // row_bcast15 -> rows 1,3
  x = dpp_add<0x143, 0xC>(x);   // row_bcast31 -> rows 2,3 (lane63 = total)
  return __int_as_float(__builtin_amdgcn_readlane(__float_as_int(x), 63));
}

// ---------------- async global->LDS 16B ----------------
__device__ __forceinline__ void load_lds16(const void* g, void* l) {
  __builtin_amdgcn_global_load_lds((const __attribute__((address_space(1))) unsigned int*)g,
                                   (__attribute__((address_space(3))) unsigned int*)l,
                                   16, 0, 0);
}

// ---------------- block reductions ----------------
__device__ __forceinline__ float block_reduce_sum(float v, float* red) {
  int t = threadIdx.x;
  red[t] = v; __syncthreads();
  for (int s = blockDim.x >> 1; s > 0; s >>= 1) {
    if (t < s) red[t] += red[t + s];
    __syncthreads();
  }
  float r = red[0]; __syncthreads();
  return r;
}
__device__ __forceinline__ float block_reduce_max(float v, float* red) {
  int t = threadIdx.x;
  red[t] = v; __syncthreads();
  for (int s = blockDim.x >> 1; s > 0; s >>= 1) {
    if (t < s) red[t] = fmaxf(red[t], red[t + s]);
    __syncthreads();
  }
  float r = red[0]; __syncthreads();
  return r;
}

// ---------------- CSR setup ----------------
__global__ void k_deg(const int* __restrict__ dst, int* __restrict__ deg) {
  int e = blockIdx.x * blockDim.x + threadIdx.x;
  if (e < N_EDGES) atomicAdd(&deg[dst[e]], 1);
}

// single-block exclusive scan, shfl wave-scan version
__global__ void k_scan(const int* __restrict__ cnt, int* __restrict__ offs, int n) {
  __shared__ int wsum[8];
  __shared__ int carry_s;
  int t = threadIdx.x, w = t >> 6, lane = t & 63;
  if (t == 0) carry_s = 0;
  __syncthreads();
  for (int base = 0; base < n; base += 256) {
    int i = base + t;
    int v = (i < n) ? cnt[i] : 0;
    int x = v;
#pragma unroll
    for (int off = 1; off < 64; off <<= 1) {
      int u = __shfl_up(x, off);
      if (lane >= off) x += u;
    }
    if (lane == 63) wsum[w] = x;
    __syncthreads();
    int wpre = 0;
    for (int q = 0; q < w; q++) wpre += wsum[q];
    int carry = carry_s;
    if (i < n) offs[i] = carry + wpre + x - v;
    __syncthreads();
    if (t == 255) carry_s = carry + wpre + x;
    __syncthreads();
  }
  if (t == 0) offs[n] = carry_s;
}

// fill CSR (edges scattered, self-loop tail direct)
__global__ void k_fill(const int* __restrict__ src, const int* __restrict__ dst,
                       const int* __restrict__ row_start, int* __restrict__ cursor,
                       int* __restrict__ csr_eid, int* __restrict__ csr_src) {
  int e = blockIdx.x * blockDim.x + threadIdx.x;
  if (e < N_EDGES) {
    int d = dst[e];
    int pos = atomicAdd(&cursor[d], 1);
    int q = row_start[d] + pos;
    csr_eid[q] = e;
    csr_src[q] = src[e];
  } else if (e < EA) {
    csr_src[e] = e - N_EDGES;
  }
}

__global__ void k_loop_attr(const float* __restrict__ edge_attr, const int* __restrict__ row_start,
                            const int* __restrict__ csr_eid, float* __restrict__ loop_attr) {
  int t = blockIdx.x * blockDim.x + threadIdx.x;
  if (t >= N_NODES * BOND) return;
  int i = t / BOND, k = t % BOND;
  int beg = row_start[i], end = row_start[i + 1];
  float s = 0.f;
  for (int p = beg; p < end; p++) s += edge_attr[(size_t)csr_eid[p] * BOND + k];
  int degv = end - beg;
  loop_attr[(size_t)i * BOND + k] = s / fmaxf((float)degv, 1.f);
}

// CSR-ordered f16 feature table: feat16[p][k2] = (f16 pair), 8 uints (32B) per position
__global__ void k_feat(const float* __restrict__ edge_attr, const float* __restrict__ loop_attr,
                       const int* __restrict__ csr_eid, unsigned* __restrict__ feat16) {
  int t = blockIdx.x * blockDim.x + threadIdx.x;
  if (t >= EA * 8) return;
  int p = t >> 3, k2 = t & 7;
  unsigned v = 0;
  if (k2 < 7) {
    const float* sp = (p < N_EDGES) ? (edge_attr + (size_t)csr_eid[p] * BOND)
                                    : (loop_attr + (size_t)(p - N_EDGES) * BOND);
    v = f2h2(sp[2 * k2], sp[2 * k2 + 1]);
  }
  feat16[(size_t)p * 8 + k2] = v;
}

// ---------------- build Bt: [L][4096][256] bf16 of [Wl|Wr]^T (coalesced) ----------------
__global__ __launch_bounds__(256) void k_build_bt(const float* __restrict__ Wl,
                                                  const float* __restrict__ Wr,
                                                  ushort_t* __restrict__ Bt) {
  __shared__ ushort_t s[64 * 40];
  int l = blockIdx.x >> 6;
  int n0 = (blockIdx.x & 63) * 64;
  int t = threadIdx.x;
  int nl = t & 63;
  int kr = t >> 6;
  int n = n0 + nl;
  const float* Wsrc = (n < HH) ? Wl : Wr;
  int nn = (n < HH) ? n : n - HH;
  const float* base = Wsrc + (size_t)l * HDIM * HH + nn;
  for (int kb = 0; kb < 256; kb += 32) {
#pragma unroll
    for (int q = 0; q < 8; q++) {
      int k = kb + q * 4 + kr;
      s[nl * 40 + q * 4 + kr] = f2bf(base[(size_t)k * HH]);
    }
    __syncthreads();
    {
      int n2 = t >> 2, c = t & 3;
      short8 v = *(const short8*)&s[n2 * 40 + c * 8];
      *(short8*)&Bt[((size_t)l * 4096 + n0 + n2) * 256 + kb + c * 8] = v;
    }
    __syncthreads();
  }
}

// ---------------- embedding: Linear -> LN -> ReLU, writes h + Abuf ----------------
__global__ __launch_bounds__(256) void k_embed(const float* __restrict__ x, const float* __restrict__ W,
                                               const float* __restrict__ b, const float* __restrict__ g,
                                               const float* __restrict__ beta, float* __restrict__ h,
                                               ushort_t* __restrict__ Abuf) {
  __shared__ float xs[ATOM];
  __shared__ float red[256];
  int i = blockIdx.x, j = threadIdx.x;
  if (j < ATOM) xs[j] = x[(size_t)i * ATOM + j];
  __syncthreads();
  float acc = b[j];
  for (int k = 0; k < ATOM; k++) acc += xs[k] * W[(size_t)k * HDIM + j];
  float mean = block_reduce_sum(acc, red) * (1.f / HDIM);
  float diff = acc - mean;
  float var = block_reduce_sum(diff * diff, red) * (1.f / HDIM);
  float vn = diff * rsqrtf(var + LN_EPS) * g[j] + beta[j];
  float r = fmaxf(vn, 0.f);
  h[(size_t)i * HDIM + j] = r;
  Abuf[(size_t)i * 256 + j] = f2bf(r);
}

// ---------------- MFMA GEMM: C[8064x4096] = A[Mx256] @ B[256x4096], bf16 in/out ----------------
// BK=32 double-buffer: 2 x 16KB stages; stage = 128 rows x 32 ushorts (4 x 16B/row).
// LDS block 34.8KB (Cs epilogue overlay dominates) -> 4 blocks/CU.
__global__ __launch_bounds__(256) void k_gemm_mfma(const ushort_t* __restrict__ A,
                                                   const ushort_t* __restrict__ Bt,
                                                   ushort_t* __restrict__ C) {
  __shared__ char smem[34816];
  ushort_t* Cs = (ushort_t*)smem;                   // [128][136] epilogue overlay
  const int tid = threadIdx.x;
  const int wave = tid >> 6, lane = tid & 63;
  const int bm = blockIdx.y * 128, bn = blockIdx.x * 128;
  const int wm = (wave >> 1) * 64, wn = (wave & 1) * 64;

  const ushort_t* agA[2];
  const ushort_t* agB[2];
  int lofs[2];
#pragma unroll
  for (int j = 0; j < 2; j++) {
    int c = j * 256 + tid;
    int row = c >> 2, col = (c & 3) * 8;
    agA[j] = A  + (size_t)(bm + row) * 256 + col;
    agB[j] = Bt + (size_t)(bn + row) * 256 + col;
    lofs[j] = c * 8;
  }

#pragma unroll
  for (int j = 0; j < 2; j++) load_lds16(agA[j], (ushort_t*)smem + lofs[j]);
#pragma unroll
  for (int j = 0; j < 2; j++) load_lds16(agB[j], (ushort_t*)(smem + 8192) + lofs[j]);

  floatx4 acc[4][4] = {};
  const int mrow = lane & 15;
  const int kq = (lane >> 4) * 8;

  for (int s = 0; s < 8; s++) {
    __syncthreads();
    if (s < 7) {
      char* nb = smem + ((s + 1) & 1) * 16384;
      const int k0 = (s + 1) * 32;
#pragma unroll
      for (int j = 0; j < 2; j++) load_lds16(agA[j] + k0, (ushort_t*)nb + lofs[j]);
#pragma unroll
      for (int j = 0; j < 2; j++) load_lds16(agB[j] + k0, (ushort_t*)(nb + 8192) + lofs[j]);
    }
    const ushort_t* As = (const ushort_t*)(smem + (s & 1) * 16384);
    const ushort_t* Bs = As + 4096;
    short8 af[4], bfr[4];
#pragma unroll
    for (int mi = 0; mi < 4; mi++)
      af[mi] = *(const short8*)&As[(wm + mi * 16 + mrow) * 32 + kq];
#pragma unroll
    for (int ni = 0; ni < 4; ni++)
      bfr[ni] = *(const short8*)&Bs[(wn + ni * 16 + mrow) * 32 + kq];
#pragma unroll
    for (int mi = 0; mi < 4; mi++)
#pragma unroll
      for (int ni = 0; ni < 4; ni++)
        acc[mi][ni] = __builtin_amdgcn_mfma_f32_16x16x32_bf16(af[mi], bfr[ni], acc[mi][ni], 0, 0, 0);
  }
  __syncthreads();
  const int lr = (lane >> 4) * 4, lc = lane & 15;
#pragma unroll
  for (int mi = 0; mi < 4; mi++)
#pragma unroll
    for (int ni = 0; ni < 4; ni++)
#pragma unroll
      for (int r = 0; r < 4; r++)
        Cs[(wm + mi * 16 + lr + r) * 136 + wn + ni * 16 + lc] = f2bf(acc[mi][ni][r]);
  __syncthreads();
#pragma unroll
  for (int it = 0; it < 8; it++) {
    int idx = it * 256 + tid;
    int row = idx >> 4, chunk = idx & 15;
    int grow = bm + row;
    if (grow < N_NODES) {
      short8 v = *(const short8*)&Cs[row * 136 + chunk * 8];
      *(short8*)&C[(size_t)grow * 4096 + bn + chunk * 8] = v;
    }
  }
}

// ---------------- fused attention + head-mean + bias + residual + LN ----------------
// Score returns a wave-uniform scalar (DPP reduce + readlane).
__device__ __forceinline__ float score_f16(const float4& xl, const float4& xr,
                                           const uint4& cfa, const uint4& cfb,
                                           const unsigned w2[7][4], const float4& at4) {
  float e0 = 0.f, e1 = 0.f, e2 = 0.f, e3 = 0.f;
  unsigned cf[7] = {cfa.x, cfa.y, cfa.z, cfa.w, cfb.x, cfb.y, cfb.z};
#pragma unroll
  for (int k2 = 0; k2 < 7; k2++) {
    h2_t f = u2h2(cf[k2]);
    e0 = FDOT2(f, u2h2(w2[k2][0]), e0);
    e1 = FDOT2(f, u2h2(w2[k2][1]), e1);
    e2 = FDOT2(f, u2h2(w2[k2][2]), e2);
    e3 = FDOT2(f, u2h2(w2[k2][3]), e3);
  }
  float f0 = xl.x + xr.x + e0; f0 = f0 > 0.f ? f0 : NEG * f0;
  float f1 = xl.y + xr.y + e1; f1 = f1 > 0.f ? f1 : NEG * f1;
  float f2 = xl.z + xr.z + e2; f2 = f2 > 0.f ? f2 : NEG * f2;
  float f3 = xl.w + xr.w + e3; f3 = f3 > 0.f ? f3 : NEG * f3;
  float sp = f0 * at4.x + f1 * at4.y + f2 * at4.z + f3 * at4.w;
  return wave_sum_u(sp);
}

// block = 512 threads = 8 waves (one per head); 2 nodes per block; grid = 4000.
// R12 single-chain structure (best validated): feat16 CSR-ordered, dot2 ee
// matvec, depth-1 prefetch, wave-uniform single-exp online softmax.
__global__ __launch_bounds__(512) void k_attn(const ushort_t* __restrict__ xlr,
    const unsigned* __restrict__ feat16,
    const float* __restrict__ We, const float* __restrict__ att,
    const int* __restrict__ row_start, const int* __restrict__ csr_src,
    const float* __restrict__ bias, const float* __restrict__ lng,
    const float* __restrict__ lnb,
    float* __restrict__ h, ushort_t* __restrict__ Abuf) {
  __shared__ ushort_t sacc[2][HEADS][264];
  const int tid = threadIdx.x, hh = tid >> 6, lane = tid & 63;
  unsigned w2[7][4];
#pragma unroll
  for (int k2 = 0; k2 < 7; k2++) {
    float4 a = *(const float4*)&We[(size_t)(2 * k2) * HH + hh * HDIM + lane * 4];
    float4 b = *(const float4*)&We[(size_t)(2 * k2 + 1) * HH + hh * HDIM + lane * 4];
    w2[k2][0] = f2h2(a.x, b.x); w2[k2][1] = f2h2(a.y, b.y);
    w2[k2][2] = f2h2(a.z, b.z); w2[k2][3] = f2h2(a.w, b.w);
  }
  float4 at4 = *(const float4*)&att[hh * HDIM + lane * 4];
  const int node0 = blockIdx.x * 2;

#pragma unroll
  for (int ni = 0; ni < 2; ni++) {
    int i = node0 + ni;
    int beg = row_start[i], end = row_start[i + 1];
    float4 xr4 = ldbf4(&xlr[(size_t)i * 4096 + 2048 + hh * HDIM + lane * 4]);
    float4 xl4 = ldbf4(&xlr[(size_t)i * 4096 + hh * HDIM + lane * 4]);
    int pself = N_EDGES + i;
    uint4 fa = *(const uint4*)&feat16[(size_t)pself * 8];
    uint4 fb = *(const uint4*)&feat16[(size_t)pself * 8 + 4];
    // prefetch first edge (depth-1)
    float4 px4;
    uint4 pfa, pfb;
    if (beg < end) {
      int sn0 = __builtin_amdgcn_readfirstlane(csr_src[beg]);
      px4 = ldbf4(&xlr[(size_t)sn0 * 4096 + hh * HDIM + lane * 4]);
      pfa = *(const uint4*)&feat16[(size_t)beg * 8];
      pfb = *(const uint4*)&feat16[(size_t)beg * 8 + 4];
    }
    float s = score_f16(xl4, xr4, fa, fb, w2, at4);   // uniform
    float m = s, l = 1.f;
    float o0 = xl4.x, o1 = xl4.y, o2 = xl4.z, o3 = xl4.w;
    for (int p = beg; p < end; p++) {
      float4 x4 = px4;
      uint4 cfa = pfa, cfb = pfb;
      if (p + 1 < end) {
        int sn = __builtin_amdgcn_readfirstlane(csr_src[p + 1]);
        px4 = ldbf4(&xlr[(size_t)sn * 4096 + hh * HDIM + lane * 4]);
        pfa = *(const uint4*)&feat16[(size_t)(p + 1) * 8];
        pfb = *(const uint4*)&feat16[(size_t)(p + 1) * 8 + 4];
      }
      float s2 = score_f16(x4, xr4, cfa, cfb, w2, at4);   // uniform
      if (s2 > m) {
        // rare path: new max -> rescale, new edge has weight 1
        float c = __expf(m - s2);
        o0 = o0 * c + x4.x; o1 = o1 * c + x4.y;
        o2 = o2 * c + x4.z; o3 = o3 * c + x4.w;
        l = l * c + 1.f;
        m = s2;
      } else {
        // common path: single exp, no rescale
        float wv = __expf(s2 - m);
        o0 += wv * x4.x; o1 += wv * x4.y;
        o2 += wv * x4.z; o3 += wv * x4.w;
        l += wv;
      }
    }
    float inv = 1.f / l;
    ushort4 st;
    st.x = f2bf(o0 * inv); st.y = f2bf(o1 * inv);
    st.z = f2bf(o2 * inv); st.w = f2bf(o3 * inv);
    *(ushort4*)&sacc[ni][hh][lane * 4] = st;
  }
  __syncthreads();
  if (hh < 2) {
    int i = node0 + hh;
    float4 hres = *(const float4*)&h[(size_t)i * HDIM + lane * 4];
    float hr[4] = {hres.x, hres.y, hres.z, hres.w};
    float v[4] = {0.f, 0.f, 0.f, 0.f};
#pragma unroll
    for (int q = 0; q < HEADS; q++) {
      ushort4 u = *(const ushort4*)&sacc[hh][q][lane * 4];
      v[0] += bf2f(u.x); v[1] += bf2f(u.y); v[2] += bf2f(u.z); v[3] += bf2f(u.w);
    }
    float4 bias4 = *(const float4*)&bias[lane * 4];
    float bi[4] = {bias4.x, bias4.y, bias4.z, bias4.w};
#pragma unroll
    for (int j = 0; j < 4; j++) v[j] = v[j] * 0.125f + bi[j] + hr[j];
    float mean = wave_sum_u(v[0] + v[1] + v[2] + v[3]) * (1.f / HDIM);
    float df[4], vr = 0.f;
#pragma unroll
    for (int j = 0; j < 4; j++) { df[j] = v[j] - mean; vr += df[j] * df[j]; }
    float rstd = rsqrtf(wave_sum_u(vr) * (1.f / HDIM) + LN_EPS);
    float4 g4 = *(const float4*)&lng[lane * 4];
    float4 b4 = *(const float4*)&lnb[lane * 4];
    float gg[4] = {g4.x, g4.y, g4.z, g4.w};
    float bb[4] = {b4.x, b4.y, b4.z, b4.w};
    float r[4];
    ushort4 hi;
#pragma unroll
    for (int j = 0; j < 4; j++) r[j] = df[j] * rstd * gg[j] + bb[j];
    hi.x = f2bf(r[0]); hi.y = f2bf(r[1]); hi.z = f2bf(r[2]); hi.w = f2bf(r[3]);
    *(float4*)&h[(size_t)i * HDIM + lane * 4] = make_float4(r[0], r[1], r[2], r[3]);
    *(ushort4*)&Abuf[(size_t)i * 256 + lane * 4] = hi;
  }
}

// ---------------- readout: gate MLP, 4 nodes per block ----------------
__global__ __launch_bounds__(128) void k_gate(const float* __restrict__ h, const float* __restrict__ g1W,
                                              const float* __restrict__ g1b, const float* __restrict__ g2W,
                                              const float* __restrict__ g2b, float* __restrict__ gate) {
  __shared__ float hs[4][HDIM];
  __shared__ float red[4][132];
  const int j = threadIdx.x;
  const int i0 = blockIdx.x * 4;
#pragma unroll
  for (int it = 0; it < 2; it++) {
    int c = it * 128 + j;
    int node = c >> 6, off = (c & 63) * 4;
    *(float4*)&hs[node][off] = *(const float4*)&h[(size_t)(i0 + node) * HDIM + off];
  }
  __syncthreads();
  float acc[4];
  float b = g1b[j];
#pragma unroll
  for (int n = 0; n < 4; n++) acc[n] = b;
  for (int k = 0; k < HDIM; k++) {
    float w = g1W[(size_t)k * (HDIM / 2) + j];
#pragma unroll
    for (int n = 0; n < 4; n++) acc[n] += hs[n][k] * w;
  }
  float w2 = g2W[j];
#pragma unroll
  for (int n = 0; n < 4; n++) red[n][j] = fmaxf(acc[n], 0.f) * w2;
  __syncthreads();
  int n = j >> 5, l2 = j & 31;
  float s = red[n][l2] + red[n][l2 + 32] + red[n][l2 + 64] + red[n][l2 + 96];
#pragma unroll
  for (int off = 16; off > 0; off >>= 1) s += __shfl_xor(s, off, 32);
  if (l2 == 0) gate[i0 + n] = s + g2b[0];
}

__global__ void k_gcount(const int* __restrict__ batch, int* __restrict__ gcnt) {
  int i = blockIdx.x * blockDim.x + threadIdx.x;
  if (i < N_NODES) atomicAdd(&gcnt[batch[i]], 1);
}

__global__ __launch_bounds__(256) void k_readout(const float* __restrict__ h, const float* __restrict__ gate,
                                                 const int* __restrict__ goff, float* __restrict__ out) {
  __shared__ float red[256];
  int b = blockIdx.x, t = threadIdx.x;
  int beg = goff[b], end = goff[b + 1];
  if (end <= beg) { out[(size_t)b * HDIM + t] = 0.f; return; }
  float lm = -3.4e38f;
  for (int i = beg + t; i < end; i += 256) lm = fmaxf(lm, gate[i]);
  float m = block_reduce_max(lm, red);
  float ls = 0.f;
  for (int i = beg + t; i < end; i += 256) ls += __expf(gate[i] - m);
  float s = block_reduce_sum(ls, red);
  float inv = 1.f / fmaxf(s, 1e-16f);
  float acc = 0.f;
  for (int i = beg; i < end; i++) acc += __expf(gate[i] - m) * h[(size_t)i * HDIM + t];
  out[(size_t)b * HDIM + t] = acc * inv;
}

// ---------------- launch ----------------
extern "C" void kernel_launch(void* const* d_in, const int* in_sizes, int n_in,
                              void* d_out, int out_size, void* d_ws, size_t ws_size,
                              hipStream_t stream) {
  const float* x         = (const float*)d_in[0];
  const float* edge_attr = (const float*)d_in[1];
  const float* emb_W     = (const float*)d_in[2];
  const float* emb_b     = (const float*)d_in[3];
  const float* emb_g     = (const float*)d_in[4];
  const float* emb_beta  = (const float*)d_in[5];
  const float* Wl        = (const float*)d_in[6];
  const float* Wr        = (const float*)d_in[7];
  const float* We        = (const float*)d_in[8];
  const float* att       = (const float*)d_in[9];
  const float* bias      = (const float*)d_in[10];
  const float* ln_g      = (const float*)d_in[11];
  const float* ln_b      = (const float*)d_in[12];
  const float* g1W       = (const float*)d_in[13];
  const float* g1b       = (const float*)d_in[14];
  const float* g2W       = (const float*)d_in[15];
  const float* g2b       = (const float*)d_in[16];
  const int*   edge_index= (const int*)d_in[17];
  const int*   batch     = (const int*)d_in[18];
  float* out = (float*)d_out;

  const int* src = edge_index;
  const int* dst = edge_index + N_EDGES;

  char* p = (char*)d_ws;
  auto alloc = [&](size_t bytes) -> void* {
    void* r = (void*)p;
    p += (bytes + 255) & ~(size_t)255;
    return r;
  };
  int*   deg       = (int*)alloc((size_t)N_NODES * 4);
  int*   row_start = (int*)alloc((size_t)(N_NODES + 1) * 4);
  int*   cursor    = (int*)alloc((size_t)N_NODES * 4);
  int*   csr_eid   = (int*)alloc((size_t)N_EDGES * 4);
  int*   csr_src   = (int*)alloc((size_t)EA * 4);
  float* loop_attr = (float*)alloc((size_t)N_NODES * BOND * 4);
  unsigned* feat16 = (unsigned*)alloc((size_t)EA * 8 * 4);
  float* h         = (float*)alloc((size_t)N_NODES * HDIM * 4);
  ushort_t* Abuf   = (ushort_t*)alloc((size_t)MPAD * 256 * 2);
  ushort_t* Bt     = (ushort_t*)alloc((size_t)NLAYERS * 4096 * 256 * 2);
  ushort_t* xlr    = (ushort_t*)alloc((size_t)N_NODES * 4096 * 2);
  float* gate      = (float*)alloc((size_t)N_NODES * 4);
  int*   gcnt      = (int*)alloc((size_t)NB * 4);
  int*   goff      = (int*)alloc((size_t)(NB + 1) * 4);

  hipMemsetAsync(deg, 0, (size_t)N_NODES * 4, stream);
  hipMemsetAsync(cursor, 0, (size_t)N_NODES * 4, stream);
  hipMemsetAsync(gcnt, 0, (size_t)NB * 4, stream);

  k_deg<<<(N_EDGES + 255) / 256, 256, 0, stream>>>(dst, deg);
  k_scan<<<1, 256, 0, stream>>>(deg, row_start, N_NODES);
  k_fill<<<(EA + 255) / 256, 256, 0, stream>>>(src, dst, row_start, cursor,
                                               csr_eid, csr_src);
  k_loop_attr<<<(N_NODES * BOND + 255) / 256, 256, 0, stream>>>(edge_attr, row_start, csr_eid, loop_attr);
  k_feat<<<(EA * 8 + 255) / 256, 256, 0, stream>>>(edge_attr, loop_attr, csr_eid, feat16);
  k_build_bt<<<NLAYERS * 64, 256, 0, stream>>>(Wl, Wr, Bt);
  k_embed<<<N_NODES, 256, 0, stream>>>(x, emb_W, emb_b, emb_g, emb_beta, h, Abuf);

  dim3 ggrid(4096 / 128, MPAD / 128);  // (32, 63)
  for (int l = 0; l < NLAYERS; l++) {
    const ushort_t* Bt_l = Bt + (size_t)l * 4096 * 256;
    const float* We_l  = We + (size_t)l * BOND * HH;
    const float* att_l = att + (size_t)l * HEADS * HDIM;
    k_gemm_mfma<<<ggrid, 256, 0, stream>>>(Abuf, Bt_l, xlr);
    k_attn<<<N_NODES / 2, 512, 0, stream>>>(xlr, feat16, We_l, att_l,
                                            row_start, csr_src,
                                            bias + (size_t)l * HDIM, ln_g + (size_t)l * HDIM,
                                            ln_b + (size_t)l * HDIM, h, Abuf);
  }

  k_gate<<<N_NODES / 4, 128, 0, stream>>>(h, g1W, g1b, g2W, g2b, gate);
  k_gcount<<<(N_NODES + 255) / 256, 256, 0, stream>>>(batch, gcnt);
  k_scan<<<1, 256, 0, stream>>>(gcnt, goff, NB);
  k_readout<<<NB, 256, 0, stream>>>(h, gate, goff, out);
}

// Round 17
// 682.268 us; speedup vs baseline: 1.1026x; 1.0382x over previous
//
#include <hip/hip_runtime.h>
#include <math.h>

#define N_NODES 8000
#define N_EDGES 24000
#define NB      256
#define ATOM    133
#define BOND    14
#define HDIM    256
#define HEADS   8
#define NLAYERS 5
#define NEG     0.2f
#define LN_EPS  1e-5f
#define HH      (HEADS * HDIM)   // 2048
#define MPAD    8064             // 63*128, padded rows for GEMM
#define EA      (N_EDGES + N_NODES)   // 32000 positions (edges + self-loops)
#define NPB     4                // nodes per attention block

typedef __attribute__((ext_vector_type(8))) short short8;
typedef __attribute__((ext_vector_type(4))) float floatx4;
typedef __attribute__((ext_vector_type(2))) _Float16 h2_t;
typedef unsigned short ushort_t;

// ---------------- bf16 helpers (RNE) ----------------
__device__ __forceinline__ ushort_t f2bf(float f) {
  unsigned u = __float_as_uint(f);
  unsigned r = (u + 0x7fff + ((u >> 16) & 1)) >> 16;
  return (ushort_t)r;
}
__device__ __forceinline__ float bf2f(ushort_t h) {
  return __uint_as_float(((unsigned)h) << 16);
}
__device__ __forceinline__ float4 ldbf4(const ushort_t* p) {
  ushort4 u = *(const ushort4*)p;
  return make_float4(bf2f(u.x), bf2f(u.y), bf2f(u.z), bf2f(u.w));
}

// ---------------- f16 pair helpers ----------------
__device__ __forceinline__ h2_t u2h2(unsigned u) {
  union { unsigned u; h2_t h; } c; c.u = u; return c.h;
}
__device__ __forceinline__ unsigned f2h2(float a, float b) {
  union { h2_t h; unsigned u; } c;
  c.h.x = (_Float16)a; c.h.y = (_Float16)b;
  return c.u;
}
#if defined(__has_builtin)
#if __has_builtin(__builtin_amdgcn_fdot2)
#define FDOT2(a, b, c) __builtin_amdgcn_fdot2((a), (b), (c), false)
#endif
#endif
#ifndef FDOT2
__device__ __forceinline__ float fdot2_sw(h2_t a, h2_t b, float c) {
  return c + (float)a.x * (float)b.x + (float)a.y * (float)b.y;
}
#define FDOT2 fdot2_sw
#endif

// ---------------- DPP full-wave sum -> uniform scalar ----------------
template <int CTRL, int RMASK>
__device__ __forceinline__ float dpp_add(float x) {
  return x + __int_as_float(__builtin_amdgcn_update_dpp(
      0, __float_as_int(x), CTRL, RMASK, 0xF, true));
}
__device__ __forceinline__ float wave_sum_u(float x) {
  x = dpp_add<0xB1, 0xF>(x);    // quad_perm [1,0,3,2]  (xor 1)
  x = dpp_add<0x4E, 0xF>(x);    // quad_perm [2,3,0,1]  (xor 2)
  x = dpp_add<0x141, 0xF>(x);   // row_half_mirror      (xor 4)
  x = dpp_add<0x140, 0xF>(x);   // row_mirror           (xor 8)
  x = dpp_add<0x142, 0xA>(x);   // row_bcast15 -> rows 1,3
  x = dpp_add<0x143, 0xC>(x);   // row_bcast31 -> rows 2,3 (lane63 = total)
  return __int_as_float(__builtin_amdgcn_readlane(__float_as_int(x), 63));
}

// ---------------- async global->LDS 16B ----------------
__device__ __forceinline__ void load_lds16(const void* g, void* l) {
  __builtin_amdgcn_global_load_lds((const __attribute__((address_space(1))) unsigned int*)g,
                                   (__attribute__((address_space(3))) unsigned int*)l,
                                   16, 0, 0);
}

// ---------------- block reductions ----------------
__device__ __forceinline__ float block_reduce_sum(float v, float* red) {
  int t = threadIdx.x;
  red[t] = v; __syncthreads();
  for (int s = blockDim.x >> 1; s > 0; s >>= 1) {
    if (t < s) red[t] += red[t + s];
    __syncthreads();
  }
  float r = red[0]; __syncthreads();
  return r;
}
__device__ __forceinline__ float block_reduce_max(float v, float* red) {
  int t = threadIdx.x;
  red[t] = v; __syncthreads();
  for (int s = blockDim.x >> 1; s > 0; s >>= 1) {
    if (t < s) red[t] = fmaxf(red[t], red[t + s]);
    __syncthreads();
  }
  float r = red[0]; __syncthreads();
  return r;
}

// ---------------- CSR setup ----------------
__global__ void k_deg(const int* __restrict__ dst, int* __restrict__ deg) {
  int e = blockIdx.x * blockDim.x + threadIdx.x;
  if (e < N_EDGES) atomicAdd(&deg[dst[e]], 1);
}

// single-block exclusive scan, shfl wave-scan version
__global__ void k_scan(const int* __restrict__ cnt, int* __restrict__ offs, int n) {
  __shared__ int wsum[8];
  __shared__ int carry_s;
  int t = threadIdx.x, w = t >> 6, lane = t & 63;
  if (t == 0) carry_s = 0;
  __syncthreads();
  for (int base = 0; base < n; base += 256) {
    int i = base + t;
    int v = (i < n) ? cnt[i] : 0;
    int x = v;
#pragma unroll
    for (int off = 1; off < 64; off <<= 1) {
      int u = __shfl_up(x, off);
      if (lane >= off) x += u;
    }
    if (lane == 63) wsum[w] = x;
    __syncthreads();
    int wpre = 0;
    for (int q = 0; q < w; q++) wpre += wsum[q];
    int carry = carry_s;
    if (i < n) offs[i] = carry + wpre + x - v;
    __syncthreads();
    if (t == 255) carry_s = carry + wpre + x;
    __syncthreads();
  }
  if (t == 0) offs[n] = carry_s;
}

// fill CSR (edges scattered, self-loop tail direct)
__global__ void k_fill(const int* __restrict__ src, const int* __restrict__ dst,
                       const int* __restrict__ row_start, int* __restrict__ cursor,
                       int* __restrict__ csr_eid, int* __restrict__ csr_src) {
  int e = blockIdx.x * blockDim.x + threadIdx.x;
  if (e < N_EDGES) {
    int d = dst[e];
    int pos = atomicAdd(&cursor[d], 1);
    int q = row_start[d] + pos;
    csr_eid[q] = e;
    csr_src[q] = src[e];
  } else if (e < EA) {
    csr_src[e] = e - N_EDGES;
  }
}

__global__ void k_loop_attr(const float* __restrict__ edge_attr, const int* __restrict__ row_start,
                            const int* __restrict__ csr_eid, float* __restrict__ loop_attr) {
  int t = blockIdx.x * blockDim.x + threadIdx.x;
  if (t >= N_NODES * BOND) return;
  int i = t / BOND, k = t % BOND;
  int beg = row_start[i], end = row_start[i + 1];
  float s = 0.f;
  for (int p = beg; p < end; p++) s += edge_attr[(size_t)csr_eid[p] * BOND + k];
  int degv = end - beg;
  loop_attr[(size_t)i * BOND + k] = s / fmaxf((float)degv, 1.f);
}

// CSR-ordered f16 feature table: feat16[p][k2] = (f16 pair), 8 uints (32B) per position
__global__ void k_feat(const float* __restrict__ edge_attr, const float* __restrict__ loop_attr,
                       const int* __restrict__ csr_eid, unsigned* __restrict__ feat16) {
  int t = blockIdx.x * blockDim.x + threadIdx.x;
  if (t >= EA * 8) return;
  int p = t >> 3, k2 = t & 7;
  unsigned v = 0;
  if (k2 < 7) {
    const float* sp = (p < N_EDGES) ? (edge_attr + (size_t)csr_eid[p] * BOND)
                                    : (loop_attr + (size_t)(p - N_EDGES) * BOND);
    v = f2h2(sp[2 * k2], sp[2 * k2 + 1]);
  }
  feat16[(size_t)p * 8 + k2] = v;
}

// ---------------- build Bt: [L][4096][256] bf16 of [Wl|Wr]^T (coalesced) ----------------
__global__ __launch_bounds__(256) void k_build_bt(const float* __restrict__ Wl,
                                                  const float* __restrict__ Wr,
                                                  ushort_t* __restrict__ Bt) {
  __shared__ ushort_t s[64 * 40];
  int l = blockIdx.x >> 6;
  int n0 = (blockIdx.x & 63) * 64;
  int t = threadIdx.x;
  int nl = t & 63;
  int kr = t >> 6;
  int n = n0 + nl;
  const float* Wsrc = (n < HH) ? Wl : Wr;
  int nn = (n < HH) ? n : n - HH;
  const float* base = Wsrc + (size_t)l * HDIM * HH + nn;
  for (int kb = 0; kb < 256; kb += 32) {
#pragma unroll
    for (int q = 0; q < 8; q++) {
      int k = kb + q * 4 + kr;
      s[nl * 40 + q * 4 + kr] = f2bf(base[(size_t)k * HH]);
    }
    __syncthreads();
    {
      int n2 = t >> 2, c = t & 3;
      short8 v = *(const short8*)&s[n2 * 40 + c * 8];
      *(short8*)&Bt[((size_t)l * 4096 + n0 + n2) * 256 + kb + c * 8] = v;
    }
    __syncthreads();
  }
}

// ---------------- embedding: Linear -> LN -> ReLU, writes h + Abuf ----------------
__global__ __launch_bounds__(256) void k_embed(const float* __restrict__ x, const float* __restrict__ W,
                                               const float* __restrict__ b, const float* __restrict__ g,
                                               const float* __restrict__ beta, float* __restrict__ h,
                                               ushort_t* __restrict__ Abuf) {
  __shared__ float xs[ATOM];
  __shared__ float red[256];
  int i = blockIdx.x, j = threadIdx.x;
  if (j < ATOM) xs[j] = x[(size_t)i * ATOM + j];
  __syncthreads();
  float acc = b[j];
  for (int k = 0; k < ATOM; k++) acc += xs[k] * W[(size_t)k * HDIM + j];
  float mean = block_reduce_sum(acc, red) * (1.f / HDIM);
  float diff = acc - mean;
  float var = block_reduce_sum(diff * diff, red) * (1.f / HDIM);
  float vn = diff * rsqrtf(var + LN_EPS) * g[j] + beta[j];
  float r = fmaxf(vn, 0.f);
  h[(size_t)i * HDIM + j] = r;
  Abuf[(size_t)i * 256 + j] = f2bf(r);
}

// ---------------- MFMA GEMM: C[8064x4096] = A[Mx256] @ B[256x4096], bf16 in/out ----------------
// BK=32 double-buffer: 2 x 16KB stages; stage = 128 rows x 32 ushorts (4 x 16B/row).
// LDS block 34.8KB (Cs epilogue overlay dominates) -> 4 blocks/CU.
__global__ __launch_bounds__(256) void k_gemm_mfma(const ushort_t* __restrict__ A,
                                                   const ushort_t* __restrict__ Bt,
                                                   ushort_t* __restrict__ C) {
  __shared__ char smem[34816];
  ushort_t* Cs = (ushort_t*)smem;                   // [128][136] epilogue overlay
  const int tid = threadIdx.x;
  const int wave = tid >> 6, lane = tid & 63;
  const int bm = blockIdx.y * 128, bn = blockIdx.x * 128;
  const int wm = (wave >> 1) * 64, wn = (wave & 1) * 64;

  const ushort_t* agA[2];
  const ushort_t* agB[2];
  int lofs[2];
#pragma unroll
  for (int j = 0; j < 2; j++) {
    int c = j * 256 + tid;
    int row = c >> 2, col = (c & 3) * 8;
    agA[j] = A  + (size_t)(bm + row) * 256 + col;
    agB[j] = Bt + (size_t)(bn + row) * 256 + col;
    lofs[j] = c * 8;
  }

#pragma unroll
  for (int j = 0; j < 2; j++) load_lds16(agA[j], (ushort_t*)smem + lofs[j]);
#pragma unroll
  for (int j = 0; j < 2; j++) load_lds16(agB[j], (ushort_t*)(smem + 8192) + lofs[j]);

  floatx4 acc[4][4] = {};
  const int mrow = lane & 15;
  const int kq = (lane >> 4) * 8;

  for (int s = 0; s < 8; s++) {
    __syncthreads();
    if (s < 7) {
      char* nb = smem + ((s + 1) & 1) * 16384;
      const int k0 = (s + 1) * 32;
#pragma unroll
      for (int j = 0; j < 2; j++) load_lds16(agA[j] + k0, (ushort_t*)nb + lofs[j]);
#pragma unroll
      for (int j = 0; j < 2; j++) load_lds16(agB[j] + k0, (ushort_t*)(nb + 8192) + lofs[j]);
    }
    const ushort_t* As = (const ushort_t*)(smem + (s & 1) * 16384);
    const ushort_t* Bs = As + 4096;
    short8 af[4], bfr[4];
#pragma unroll
    for (int mi = 0; mi < 4; mi++)
      af[mi] = *(const short8*)&As[(wm + mi * 16 + mrow) * 32 + kq];
#pragma unroll
    for (int ni = 0; ni < 4; ni++)
      bfr[ni] = *(const short8*)&Bs[(wn + ni * 16 + mrow) * 32 + kq];
#pragma unroll
    for (int mi = 0; mi < 4; mi++)
#pragma unroll
      for (int ni = 0; ni < 4; ni++)
        acc[mi][ni] = __builtin_amdgcn_mfma_f32_16x16x32_bf16(af[mi], bfr[ni], acc[mi][ni], 0, 0, 0);
  }
  __syncthreads();
  const int lr = (lane >> 4) * 4, lc = lane & 15;
#pragma unroll
  for (int mi = 0; mi < 4; mi++)
#pragma unroll
    for (int ni = 0; ni < 4; ni++)
#pragma unroll
      for (int r = 0; r < 4; r++)
        Cs[(wm + mi * 16 + lr + r) * 136 + wn + ni * 16 + lc] = f2bf(acc[mi][ni][r]);
  __syncthreads();
#pragma unroll
  for (int it = 0; it < 8; it++) {
    int idx = it * 256 + tid;
    int row = idx >> 4, chunk = idx & 15;
    int grow = bm + row;
    if (grow < N_NODES) {
      short8 v = *(const short8*)&Cs[row * 136 + chunk * 8];
      *(short8*)&C[(size_t)grow * 4096 + bn + chunk * 8] = v;
    }
  }
}

// ---------------- fused attention + head-mean + bias + residual + LN ----------------
// Score returns a wave-uniform scalar (DPP reduce + readlane).
__device__ __forceinline__ float score_f16(const float4& xl, const float4& xr,
                                           const uint4& cfa, const uint4& cfb,
                                           const unsigned w2[7][4], const float4& at4) {
  float e0 = 0.f, e1 = 0.f, e2 = 0.f, e3 = 0.f;
  unsigned cf[7] = {cfa.x, cfa.y, cfa.z, cfa.w, cfb.x, cfb.y, cfb.z};
#pragma unroll
  for (int k2 = 0; k2 < 7; k2++) {
    h2_t f = u2h2(cf[k2]);
    e0 = FDOT2(f, u2h2(w2[k2][0]), e0);
    e1 = FDOT2(f, u2h2(w2[k2][1]), e1);
    e2 = FDOT2(f, u2h2(w2[k2][2]), e2);
    e3 = FDOT2(f, u2h2(w2[k2][3]), e3);
  }
  float f0 = xl.x + xr.x + e0; f0 = f0 > 0.f ? f0 : NEG * f0;
  float f1 = xl.y + xr.y + e1; f1 = f1 > 0.f ? f1 : NEG * f1;
  float f2 = xl.z + xr.z + e2; f2 = f2 > 0.f ? f2 : NEG * f2;
  float f3 = xl.w + xr.w + e3; f3 = f3 > 0.f ? f3 : NEG * f3;
  float sp = f0 * at4.x + f1 * at4.y + f2 * at4.z + f3 * at4.w;
  return wave_sum_u(sp);
}

// block = 512 threads = 8 waves (one per head); NPB=4 nodes per block; grid = 2000.
// R12 single-chain per node (best validated); preload amortized over 4 nodes,
// LN tail uses 4 of 8 waves.
__global__ __launch_bounds__(512) void k_attn(const ushort_t* __restrict__ xlr,
    const unsigned* __restrict__ feat16,
    const float* __restrict__ We, const float* __restrict__ att,
    const int* __restrict__ row_start, const int* __restrict__ csr_src,
    const float* __restrict__ bias, const float* __restrict__ lng,
    const float* __restrict__ lnb,
    float* __restrict__ h, ushort_t* __restrict__ Abuf) {
  __shared__ ushort_t sacc[NPB][HEADS][264];
  const int tid = threadIdx.x, hh = tid >> 6, lane = tid & 63;
  unsigned w2[7][4];
#pragma unroll
  for (int k2 = 0; k2 < 7; k2++) {
    float4 a = *(const float4*)&We[(size_t)(2 * k2) * HH + hh * HDIM + lane * 4];
    float4 b = *(const float4*)&We[(size_t)(2 * k2 + 1) * HH + hh * HDIM + lane * 4];
    w2[k2][0] = f2h2(a.x, b.x); w2[k2][1] = f2h2(a.y, b.y);
    w2[k2][2] = f2h2(a.z, b.z); w2[k2][3] = f2h2(a.w, b.w);
  }
  float4 at4 = *(const float4*)&att[hh * HDIM + lane * 4];
  const int node0 = blockIdx.x * NPB;

#pragma unroll
  for (int ni = 0; ni < NPB; ni++) {
    int i = node0 + ni;
    int beg = row_start[i], end = row_start[i + 1];
    float4 xr4 = ldbf4(&xlr[(size_t)i * 4096 + 2048 + hh * HDIM + lane * 4]);
    float4 xl4 = ldbf4(&xlr[(size_t)i * 4096 + hh * HDIM + lane * 4]);
    int pself = N_EDGES + i;
    uint4 fa = *(const uint4*)&feat16[(size_t)pself * 8];
    uint4 fb = *(const uint4*)&feat16[(size_t)pself * 8 + 4];
    // prefetch first edge (depth-1)
    float4 px4;
    uint4 pfa, pfb;
    if (beg < end) {
      int sn0 = __builtin_amdgcn_readfirstlane(csr_src[beg]);
      px4 = ldbf4(&xlr[(size_t)sn0 * 4096 + hh * HDIM + lane * 4]);
      pfa = *(const uint4*)&feat16[(size_t)beg * 8];
      pfb = *(const uint4*)&feat16[(size_t)beg * 8 + 4];
    }
    float s = score_f16(xl4, xr4, fa, fb, w2, at4);   // uniform
    float m = s, l = 1.f;
    float o0 = xl4.x, o1 = xl4.y, o2 = xl4.z, o3 = xl4.w;
    for (int p = beg; p < end; p++) {
      float4 x4 = px4;
      uint4 cfa = pfa, cfb = pfb;
      if (p + 1 < end) {
        int sn = __builtin_amdgcn_readfirstlane(csr_src[p + 1]);
        px4 = ldbf4(&xlr[(size_t)sn * 4096 + hh * HDIM + lane * 4]);
        pfa = *(const uint4*)&feat16[(size_t)(p + 1) * 8];
        pfb = *(const uint4*)&feat16[(size_t)(p + 1) * 8 + 4];
      }
      float s2 = score_f16(x4, xr4, cfa, cfb, w2, at4);   // uniform
      if (s2 > m) {
        // rare path: new max -> rescale, new edge has weight 1
        float c = __expf(m - s2);
        o0 = o0 * c + x4.x; o1 = o1 * c + x4.y;
        o2 = o2 * c + x4.z; o3 = o3 * c + x4.w;
        l = l * c + 1.f;
        m = s2;
      } else {
        // common path: single exp, no rescale
        float wv = __expf(s2 - m);
        o0 += wv * x4.x; o1 += wv * x4.y;
        o2 += wv * x4.z; o3 += wv * x4.w;
        l += wv;
      }
    }
    float inv = 1.f / l;
    ushort4 st;
    st.x = f2bf(o0 * inv); st.y = f2bf(o1 * inv);
    st.z = f2bf(o2 * inv); st.w = f2bf(o3 * inv);
    *(ushort4*)&sacc[ni][hh][lane * 4] = st;
  }
  __syncthreads();
  if (hh < NPB) {
    int i = node0 + hh;
    float4 hres = *(const float4*)&h[(size_t)i * HDIM + lane * 4];
    float hr[4] = {hres.x, hres.y, hres.z, hres.w};
    float v[4] = {0.f, 0.f, 0.f, 0.f};
#pragma unroll
    for (int q = 0; q < HEADS; q++) {
      ushort4 u = *(const ushort4*)&sacc[hh][q][lane * 4];
      v[0] += bf2f(u.x); v[1] += bf2f(u.y); v[2] += bf2f(u.z); v[3] += bf2f(u.w);
    }
    float4 bias4 = *(const float4*)&bias[lane * 4];
    float bi[4] = {bias4.x, bias4.y, bias4.z, bias4.w};
#pragma unroll
    for (int j = 0; j < 4; j++) v[j] = v[j] * 0.125f + bi[j] + hr[j];
    float mean = wave_sum_u(v[0] + v[1] + v[2] + v[3]) * (1.f / HDIM);
    float df[4], vr = 0.f;
#pragma unroll
    for (int j = 0; j < 4; j++) { df[j] = v[j] - mean; vr += df[j] * df[j]; }
    float rstd = rsqrtf(wave_sum_u(vr) * (1.f / HDIM) + LN_EPS);
    float4 g4 = *(const float4*)&lng[lane * 4];
    float4 b4 = *(const float4*)&lnb[lane * 4];
    float gg[4] = {g4.x, g4.y, g4.z, g4.w};
    float bb[4] = {b4.x, b4.y, b4.z, b4.w};
    float r[4];
    ushort4 hi;
#pragma unroll
    for (int j = 0; j < 4; j++) r[j] = df[j] * rstd * gg[j] + bb[j];
    hi.x = f2bf(r[0]); hi.y = f2bf(r[1]); hi.z = f2bf(r[2]); hi.w = f2bf(r[3]);
    *(float4*)&h[(size_t)i * HDIM + lane * 4] = make_float4(r[0], r[1], r[2], r[3]);
    *(ushort4*)&Abuf[(size_t)i * 256 + lane * 4] = hi;
  }
}

// ---------------- readout: gate MLP, 4 nodes per block ----------------
__global__ __launch_bounds__(128) void k_gate(const float* __restrict__ h, const float* __restrict__ g1W,
                                              const float* __restrict__ g1b, const float* __restrict__ g2W,
                                              const float* __restrict__ g2b, float* __restrict__ gate) {
  __shared__ float hs[4][HDIM];
  __shared__ float red[4][132];
  const int j = threadIdx.x;
  const int i0 = blockIdx.x * 4;
#pragma unroll
  for (int it = 0; it < 2; it++) {
    int c = it * 128 + j;
    int node = c >> 6, off = (c & 63) * 4;
    *(float4*)&hs[node][off] = *(const float4*)&h[(size_t)(i0 + node) * HDIM + off];
  }
  __syncthreads();
  float acc[4];
  float b = g1b[j];
#pragma unroll
  for (int n = 0; n < 4; n++) acc[n] = b;
  for (int k = 0; k < HDIM; k++) {
    float w = g1W[(size_t)k * (HDIM / 2) + j];
#pragma unroll
    for (int n = 0; n < 4; n++) acc[n] += hs[n][k] * w;
  }
  float w2 = g2W[j];
#pragma unroll
  for (int n = 0; n < 4; n++) red[n][j] = fmaxf(acc[n], 0.f) * w2;
  __syncthreads();
  int n = j >> 5, l2 = j & 31;
  float s = red[n][l2] + red[n][l2 + 32] + red[n][l2 + 64] + red[n][l2 + 96];
#pragma unroll
  for (int off = 16; off > 0; off >>= 1) s += __shfl_xor(s, off, 32);
  if (l2 == 0) gate[i0 + n] = s + g2b[0];
}

__global__ void k_gcount(const int* __restrict__ batch, int* __restrict__ gcnt) {
  int i = blockIdx.x * blockDim.x + threadIdx.x;
  if (i < N_NODES) atomicAdd(&gcnt[batch[i]], 1);
}

__global__ __launch_bounds__(256) void k_readout(const float* __restrict__ h, const float* __restrict__ gate,
                                                 const int* __restrict__ goff, float* __restrict__ out) {
  __shared__ float red[256];
  int b = blockIdx.x, t = threadIdx.x;
  int beg = goff[b], end = goff[b + 1];
  if (end <= beg) { out[(size_t)b * HDIM + t] = 0.f; return; }
  float lm = -3.4e38f;
  for (int i = beg + t; i < end; i += 256) lm = fmaxf(lm, gate[i]);
  float m = block_reduce_max(lm, red);
  float ls = 0.f;
  for (int i = beg + t; i < end; i += 256) ls += __expf(gate[i] - m);
  float s = block_reduce_sum(ls, red);
  float inv = 1.f / fmaxf(s, 1e-16f);
  float acc = 0.f;
  for (int i = beg; i < end; i++) acc += __expf(gate[i] - m) * h[(size_t)i * HDIM + t];
  out[(size_t)b * HDIM + t] = acc * inv;
}

// ---------------- launch ----------------
extern "C" void kernel_launch(void* const* d_in, const int* in_sizes, int n_in,
                              void* d_out, int out_size, void* d_ws, size_t ws_size,
                              hipStream_t stream) {
  const float* x         = (const float*)d_in[0];
  const float* edge_attr = (const float*)d_in[1];
  const float* emb_W     = (const float*)d_in[2];
  const float* emb_b     = (const float*)d_in[3];
  const float* emb_g     = (const float*)d_in[4];
  const float* emb_beta  = (const float*)d_in[5];
  const float* Wl        = (const float*)d_in[6];
  const float* Wr        = (const float*)d_in[7];
  const float* We        = (const float*)d_in[8];
  const float* att       = (const float*)d_in[9];
  const float* bias      = (const float*)d_in[10];
  const float* ln_g      = (const float*)d_in[11];
  const float* ln_b      = (const float*)d_in[12];
  const float* g1W       = (const float*)d_in[13];
  const float* g1b       = (const float*)d_in[14];
  const float* g2W       = (const float*)d_in[15];
  const float* g2b       = (const float*)d_in[16];
  const int*   edge_index= (const int*)d_in[17];
  const int*   batch     = (const int*)d_in[18];
  float* out = (float*)d_out;

  const int* src = edge_index;
  const int* dst = edge_index + N_EDGES;

  char* p = (char*)d_ws;
  auto alloc = [&](size_t bytes) -> void* {
    void* r = (void*)p;
    p += (bytes + 255) & ~(size_t)255;
    return r;
  };
  int*   deg       = (int*)alloc((size_t)N_NODES * 4);
  int*   row_start = (int*)alloc((size_t)(N_NODES + 1) * 4);
  int*   cursor    = (int*)alloc((size_t)N_NODES * 4);
  int*   csr_eid   = (int*)alloc((size_t)N_EDGES * 4);
  int*   csr_src   = (int*)alloc((size_t)EA * 4);
  float* loop_attr = (float*)alloc((size_t)N_NODES * BOND * 4);
  unsigned* feat16 = (unsigned*)alloc((size_t)EA * 8 * 4);
  float* h         = (float*)alloc((size_t)N_NODES * HDIM * 4);
  ushort_t* Abuf   = (ushort_t*)alloc((size_t)MPAD * 256 * 2);
  ushort_t* Bt     = (ushort_t*)alloc((size_t)NLAYERS * 4096 * 256 * 2);
  ushort_t* xlr    = (ushort_t*)alloc((size_t)N_NODES * 4096 * 2);
  float* gate      = (float*)alloc((size_t)N_NODES * 4);
  int*   gcnt      = (int*)alloc((size_t)NB * 4);
  int*   goff      = (int*)alloc((size_t)(NB + 1) * 4);

  hipMemsetAsync(deg, 0, (size_t)N_NODES * 4, stream);
  hipMemsetAsync(cursor, 0, (size_t)N_NODES * 4, stream);
  hipMemsetAsync(gcnt, 0, (size_t)NB * 4, stream);

  k_deg<<<(N_EDGES + 255) / 256, 256, 0, stream>>>(dst, deg);
  k_scan<<<1, 256, 0, stream>>>(deg, row_start, N_NODES);
  k_fill<<<(EA + 255) / 256, 256, 0, stream>>>(src, dst, row_start, cursor,
                                               csr_eid, csr_src);
  k_loop_attr<<<(N_NODES * BOND + 255) / 256, 256, 0, stream>>>(edge_attr, row_start, csr_eid, loop_attr);
  k_feat<<<(EA * 8 + 255) / 256, 256, 0, stream>>>(edge_attr, loop_attr, csr_eid, feat16);
  k_build_bt<<<NLAYERS * 64, 256, 0, stream>>>(Wl, Wr, Bt);
  k_embed<<<N_NODES, 256, 0, stream>>>(x, emb_W, emb_b, emb_g, emb_beta, h, Abuf);

  dim3 ggrid(4096 / 128, MPAD / 128);  // (32, 63)
  for (int l = 0; l < NLAYERS; l++) {
    const ushort_t* Bt_l = Bt + (size_t)l * 4096 * 256;
    const float* We_l  = We + (size_t)l * BOND * HH;
    const float* att_l = att + (size_t)l * HEADS * HDIM;
    k_gemm_mfma<<<ggrid, 256, 0, stream>>>(Abuf, Bt_l, xlr);
    k_attn<<<N_NODES / NPB, 512, 0, stream>>>(xlr, feat16, We_l, att_l,
                                              row_start, csr_src,
                                              bias + (size_t)l * HDIM, ln_g + (size_t)l * HDIM,
                                              ln_b + (size_t)l * HDIM, h, Abuf);
  }

  k_gate<<<N_NODES / 4, 128, 0, stream>>>(h, g1W, g1b, g2W, g2b, gate);
  k_gcount<<<(N_NODES + 255) / 256, 256, 0, stream>>>(batch, gcnt);
  k_scan<<<1, 256, 0, stream>>>(gcnt, goff, NB);
  k_readout<<<NB, 256, 0, stream>>>(h, gate, goff, out);
}